// Round 14
// baseline (2985.040 us; speedup 1.0000x reference)
//
#include <hip/hip_runtime.h>
#include <hip/hip_bf16.h>
#include <math.h>
#include <float.h>

#define TN      768
#define EMBD    300
#define XPAD    304
#define LSTMD   200
#define G4      800
#define STATE   400
#define HIDD    150
#define NPADC   160
#define SPAND   1101
#define KP      1120
#define NSPANS  7635
#define NSEL    307
#define SORTN   8192

typedef unsigned long long ull;
typedef __attribute__((ext_vector_type(8))) short bf16x8;
typedef __attribute__((ext_vector_type(4))) float mf32x4;

// ---- workspace offsets (in floats) ----
#define OFF_X       0u
#define OFF_ZXF     233472u
#define OFF_ZXB     847872u
#define OFF_H       1462272u
#define OFF_ATTN    1769472u
#define OFF_I1      1770496u
#define OFF_I2      1778176u
#define OFF_SM      1785856u
#define OFF_SELK    1793536u
#define OFF_SELSPAN 1794048u
#define OFF_SMF     1794560u
#define OFF_A       1795072u
#define OFF_B       1844224u
#define OFF_WTF     1893376u
#define OFF_WTB     2133376u
#define OFF_AW1T    2373376u
#define OFF_AW2T    2437376u
#define OFF_SW1T    2461376u
#define OFF_SW2T    2640576u
#define OFF_PW1AT   2664576u
#define OFF_PW1BT   2843776u
#define OFF_G       3226176u
#define OFF_PW1CB   11777376u   /* bf16 [160][1120] = 89600 floats */
#define OFF_PW2B    11866976u   /* bf16 [160][160]  = 12800 floats */
// hqL2 + hqL3 mailboxes + ctrl alias the head of the G region (k_spans
// overwrites g rows strictly after the LSTM in stream order).

#define REP50(M) M(0) M(1) M(2) M(3) M(4) M(5) M(6) M(7) M(8) M(9) \
 M(10) M(11) M(12) M(13) M(14) M(15) M(16) M(17) M(18) M(19) \
 M(20) M(21) M(22) M(23) M(24) M(25) M(26) M(27) M(28) M(29) \
 M(30) M(31) M(32) M(33) M(34) M(35) M(36) M(37) M(38) M(39) \
 M(40) M(41) M(42) M(43) M(44) M(45) M(46) M(47) M(48) M(49)

__device__ __forceinline__ float sigf(float x) { return 1.f / (1.f + __expf(-x)); }
__device__ __forceinline__ float tanhf_(float x) {
    x = fminf(15.f, fmaxf(-15.f, x));
    float e = __expf(2.f * x);
    return (e - 1.f) / (e + 1.f);
}
__device__ __forceinline__ unsigned short f2bf(float v) {
    __hip_bfloat16 h = __float2bfloat16(v);
    return *(unsigned short*)&h;
}

// ---------------- fused gather + Wih transposes (sequential, pre-LSTM) -----
__global__ void k_pre0(const int* __restrict__ tokens, const float* __restrict__ emb,
                       float* __restrict__ x, const float* __restrict__ Wih_f,
                       const float* __restrict__ Wih_b, float* __restrict__ wtf,
                       float* __restrict__ wtb) {
    int b = blockIdx.x, tid = threadIdx.x;
    if (b < TN) {
        int tok = tokens[b];
        for (int d = tid; d < XPAD; d += 256)
            x[b * XPAD + d] = (d < EMBD) ? emb[(size_t)tok * EMBD + d] : 0.f;
    } else if (b < TN + 1200) {
        int bb = b - TN;
        int k = bb >> 2, n = ((bb & 3) << 8) + tid;
        if (n < G4) wtf[(size_t)k * G4 + n] = Wih_f[(size_t)n * EMBD + k];
    } else {
        int bb = b - TN - 1200;
        int k = bb >> 2, n = ((bb & 3) << 8) + tid;
        if (n < G4) wtb[(size_t)k * G4 + n] = Wih_b[(size_t)n * EMBD + k];
    }
}

// ---------------- fused small-weight prep (sequential, pre-LSTM) ----------
__device__ void prep_tr(const float* __restrict__ src, float* __restrict__ dst,
                        int N, int K, int stride, int off, int Npad, int totalK,
                        int part, int nparts, int tid) {
    int total = totalK * Npad;
    for (int idx = part * 256 + tid; idx < total; idx += nparts * 256) {
        int k = idx / Npad, n = idx - k * Npad;
        dst[idx] = (k < K && n < N) ? src[(size_t)n * stride + off + k] : 0.f;
    }
}
__device__ void prep_bf(const float* __restrict__ src, unsigned short* __restrict__ dst,
                        int R, int C, int stride, int off, int NR, int NC,
                        int part, int nparts, int tid) {
    int total = NR * NC;
    for (int idx = part * 256 + tid; idx < total; idx += nparts * 256) {
        int r = idx / NC, c = idx - r * NC;
        float v = (r < R && c < C) ? src[(size_t)r * stride + off + c] : 0.f;
        dst[idx] = f2bf(v);
    }
}
__global__ void k_pre1(const float* __restrict__ aW1, const float* __restrict__ aW2,
                       const float* __restrict__ sW1, const float* __restrict__ sW2,
                       const float* __restrict__ pW1, const float* __restrict__ pW2,
                       float* __restrict__ aW1T, float* __restrict__ aW2T,
                       float* __restrict__ sW1T, float* __restrict__ sW2T,
                       float* __restrict__ pW1AT, float* __restrict__ pW1BT,
                       unsigned short* __restrict__ pw1cb,
                       unsigned short* __restrict__ pw2b) {
    int p = blockIdx.x, tid = threadIdx.x;
    if (p < 4)       prep_tr(aW1, aW1T, 150, 400, 400, 0, 160, 400, p, 4, tid);
    else if (p < 6)  prep_tr(aW2, aW2T, 150, 150, 150, 0, 160, 150, p - 4, 2, tid);
    else if (p < 18) prep_tr(sW1, sW1T, 150, SPAND, SPAND, 0, 160, KP, p - 6, 12, tid);
    else if (p < 20) prep_tr(sW2, sW2T, 150, 150, 150, 0, 160, 150, p - 18, 2, tid);
    else if (p < 32) prep_tr(pW1, pW1AT, 150, SPAND, 3303, 0, 160, KP, p - 20, 12, tid);
    else if (p < 44) prep_tr(pW1, pW1BT, 150, SPAND, 3303, 1101, 160, KP, p - 32, 12, tid);
    else if (p < 56) prep_bf(pW1, pw1cb, 150, SPAND, 3303, 2202, 160, KP, p - 44, 12, tid);
    else             prep_bf(pW2, pw2b, 150, 150, 150, 0, 160, 160, p - 56, 2, tid);
}

// ---------------- input projections zx = x @ Wih^T + b ----------------
__global__ void k_zx(const float* __restrict__ x, const float* __restrict__ WTf,
                     const float* __restrict__ WTb, const float* __restrict__ bf,
                     const float* __restrict__ bb, float* __restrict__ zxf,
                     float* __restrict__ zxb) {
    __shared__ float xl[8 * XPAD];
    int tid = threadIdx.x;
    int bm = blockIdx.x, dir = blockIdx.y;
    for (int l = tid; l < 8 * XPAD; l += 256) xl[l] = x[(size_t)(bm * 8) * XPAD + l];
    __syncthreads();
    const float* WT = dir ? WTb : WTf;
    const float* bv = dir ? bb : bf;
    float* zx = dir ? zxb : zxf;
    for (int jj = 0; jj < 4; ++jj) {
        int n = tid + 256 * jj;
        if (n >= G4) break;
        float acc[8] = {0, 0, 0, 0, 0, 0, 0, 0};
        for (int k = 0; k < EMBD; ++k) {
            float wv = WT[(size_t)k * G4 + n];
#pragma unroll
            for (int r = 0; r < 8; ++r) acc[r] = fmaf(xl[r * XPAD + k], wv, acc[r]);
        }
        float bias = bv[n];
#pragma unroll
        for (int r = 0; r < 8; ++r) {
            int row = bm * 8 + r;
            int trow = dir ? (TN - 1 - row) : row;
            zx[(size_t)trow * G4 + n] = acc[r] + bias;
        }
    }
}

// ---------------- BiLSTM: R12 base + 4-accumulator dot (publish-path cut) --
// ONLY change vs R12: the 200-deep dependent fmaf chain is split into 4
// independent accumulators (one per float4 component), cutting the exposed
// latency before zl/publish from ~800cyc to ~250cyc. Prefetch stays in the
// R12 position (after barrier1) — R13 proved moving it earlier delays the
// publish and regresses.
__global__ __launch_bounds__(256, 1) void k_lstm_mb8(const float* __restrict__ zxf,
                                                     const float* __restrict__ zxb,
                                                     const float* __restrict__ Whh_f,
                                                     const float* __restrict__ Whh_b,
                                                     float* __restrict__ hcat,
                                                     ull* __restrict__ hqL2,
                                                     ull* __restrict__ hqL3,
                                                     int* __restrict__ ctrl) {
    int blk = blockIdx.x;
    int lane8 = blk & 7;
    if (lane8 >= 2) return;
    int dir = lane8, b = blk >> 3;
    int tid = threadIdx.x;
    __shared__ int s_mode;
    if (tid == 0) {
        unsigned xcc;
        asm volatile("s_getreg_b32 %0, hwreg(HW_REG_XCC_ID)" : "=s"(xcc));
        xcc &= 7u;
        __hip_atomic_store(&ctrl[dir * 4 + b], (int)(1u + xcc), __ATOMIC_RELAXED,
                           __HIP_MEMORY_SCOPE_AGENT);
        int v0, v1, v2, v3;
        do {
            v0 = __hip_atomic_load(&ctrl[dir * 4 + 0], __ATOMIC_RELAXED,
                                   __HIP_MEMORY_SCOPE_AGENT);
            v1 = __hip_atomic_load(&ctrl[dir * 4 + 1], __ATOMIC_RELAXED,
                                   __HIP_MEMORY_SCOPE_AGENT);
            v2 = __hip_atomic_load(&ctrl[dir * 4 + 2], __ATOMIC_RELAXED,
                                   __HIP_MEMORY_SCOPE_AGENT);
            v3 = __hip_atomic_load(&ctrl[dir * 4 + 3], __ATOMIC_RELAXED,
                                   __HIP_MEMORY_SCOPE_AGENT);
        } while (!v0 || !v1 || !v2 || !v3);
        s_mode = (v0 == v1 && v1 == v2 && v2 == v3) ? 1 : 0;
    }
    __syncthreads();
    int mode = s_mode;  // 1 = XCD-local L2 exchange; 0 = L3 (R4 path)

    const float* zx = dir ? zxb : zxf;
    const float* Whh = dir ? Whh_b : Whh_f;
    ull* hq2d = hqL2 + (size_t)dir * TN * 256;
    ull* hq3d = hqL3 + (size_t)dir * TN * 256;
    __shared__ __align__(16) float hprev[LSTMD];
    __shared__ float zl[200];
    bool active = tid < 200;
    int q = tid / 50, u = tid % 50;
    int gr_row = q * 200 + b * 50 + u;
    int grs = active ? gr_row : 0;
    const float4* wr = (const float4*)(Whh + (size_t)grs * LSTMD);
#define WDECL(i) float4 w##i = wr[i];
    REP50(WDECL)
#undef WDECL
    float c = 0.f;
    for (int l = tid; l < LSTMD; l += 256) hprev[l] = 0.f;
    int remote_idx = (tid < b * 50) ? tid : tid + 50;
    __syncthreads();
    float zpre = zx[grs];
    for (int t = 0; t < TN; ++t) {
        float a0 = zpre, a1 = 0.f, a2 = 0.f, a3 = 0.f;
        const float4* h4 = (const float4*)hprev;
#define WFMA(i) { float4 hv = h4[i]; \
        a0 = fmaf(w##i.x, hv.x, a0); a1 = fmaf(w##i.y, hv.y, a1); \
        a2 = fmaf(w##i.z, hv.z, a2); a3 = fmaf(w##i.w, hv.w, a3); }
        REP50(WFMA)
#undef WFMA
        if (active) zl[tid] = (a0 + a1) + (a2 + a3);
        __syncthreads();
        int trow = dir ? (TN - 1 - t) : t;
        if (tid < 50) {
            float zi = zl[tid], zf = zl[50 + tid], zg = zl[100 + tid], zo = zl[150 + tid];
            c = sigf(zf) * c + sigf(zi) * tanhf_(zg);
            float h = sigf(zo) * tanhf_(c);
            hcat[(size_t)trow * STATE + dir * LSTMD + b * 50 + tid] = h;
            hprev[b * 50 + tid] = h;
            if (t + 1 < TN) {
                ull pk = (ull)__float_as_uint(h) | ((ull)(unsigned)(t + 1) << 32);
                size_t slot = (size_t)t * 256 + b * 50 + tid;
                if (mode) {
                    (void)__hip_atomic_exchange(&hq2d[slot], pk, __ATOMIC_RELAXED,
                                                __HIP_MEMORY_SCOPE_WORKGROUP);
                } else {
                    __hip_atomic_store(&hq3d[slot], pk, __ATOMIC_RELAXED,
                                       __HIP_MEMORY_SCOPE_AGENT);
                }
            }
        }
        if (t + 1 < TN) {
            zpre = zx[(size_t)(t + 1) * G4 + grs];  // R12 position: after barrier1
            if (tid < 150) {
                size_t slot = (size_t)t * 256 + remote_idx;
                ull v;
                if (mode) {
                    for (;;) {
                        ull probe = ~0ull;  // impossible tag: CAS fails, returns
                                            // current value — guaranteed L2 RMW
                        __hip_atomic_compare_exchange_strong(
                            &hq2d[slot], &probe, ~0ull, __ATOMIC_RELAXED,
                            __ATOMIC_RELAXED, __HIP_MEMORY_SCOPE_WORKGROUP);
                        if ((unsigned)(probe >> 32) == (unsigned)(t + 1)) {
                            v = probe; break;
                        }
                    }
                } else {
                    do {
                        v = __hip_atomic_load(&hq3d[slot], __ATOMIC_RELAXED,
                                              __HIP_MEMORY_SCOPE_AGENT);
                    } while ((unsigned)(v >> 32) != (unsigned)(t + 1));
                }
                hprev[remote_idx] = __uint_as_float((unsigned)v);
            }
            __syncthreads();
        }
    }
}

// ---------------- attention FFNN: per-token scalar ----------------
__global__ void k_attn(const float* __restrict__ hcat, const float* __restrict__ aW1T,
                       const float* __restrict__ ab1, const float* __restrict__ aW2T,
                       const float* __restrict__ ab2, const float* __restrict__ aW3,
                       const float* __restrict__ ab3, float* __restrict__ attn) {
    __shared__ float hrow[STATE];
    __shared__ float l1[NPADC];
    __shared__ float l2[NPADC];
    __shared__ float red[256];
    int t = blockIdx.x, tid = threadIdx.x;
    for (int d = tid; d < STATE; d += 256) hrow[d] = hcat[(size_t)t * STATE + d];
    __syncthreads();
    if (tid < HIDD) {
        float acc = ab1[tid];
        for (int k = 0; k < STATE; ++k) acc = fmaf(hrow[k], aW1T[(size_t)k * NPADC + tid], acc);
        l1[tid] = fmaxf(acc, 0.f);
    }
    __syncthreads();
    if (tid < HIDD) {
        float acc = ab2[tid];
        for (int k = 0; k < HIDD; ++k) acc = fmaf(l1[k], aW2T[(size_t)k * NPADC + tid], acc);
        l2[tid] = fmaxf(acc, 0.f);
    }
    __syncthreads();
    float partial = (tid < HIDD) ? l2[tid] * aW3[tid] : 0.f;
    red[tid] = partial;
    __syncthreads();
    for (int s = 128; s > 0; s >>= 1) {
        if (tid < s) red[tid] += red[tid + s];
        __syncthreads();
    }
    if (tid == 0) attn[t] = red[0] + ab3[0];
}

// ---------------- span construction: g rows + i1/i2 ----------------
__global__ void k_spans(const float* __restrict__ attn, const float* __restrict__ hcat,
                        const float* __restrict__ x, float* __restrict__ g,
                        int* __restrict__ i1s, int* __restrict__ i2s) {
    int s = blockIdx.x;
    int n = 1, base = 0;
    while (s >= base + (TN - n + 1)) { base += TN - n + 1; n++; }
    int a = s - base, b = a + n - 1;
    int lane = threadIdx.x;
    float e[10];
    float mx = -FLT_MAX;
#pragma unroll
    for (int k = 0; k < 10; ++k)
        if (k < n) { e[k] = attn[a + k]; mx = fmaxf(mx, e[k]); }
    float ssum = 0.f;
#pragma unroll
    for (int k = 0; k < 10; ++k)
        if (k < n) { e[k] = __expf(e[k] - mx); ssum += e[k]; }
    float w[10];
#pragma unroll
    for (int k = 0; k < 10; ++k) w[k] = (k < n) ? e[k] / ssum : 0.f;

    float* grow = g + (size_t)s * KP;
    for (int d = lane; d < STATE; d += 64) grow[d] = hcat[(size_t)a * STATE + d];
    for (int d = lane; d < STATE; d += 64) grow[STATE + d] = hcat[(size_t)b * STATE + d];
    for (int d = lane; d < EMBD; d += 64) {
        float p = 0.f;
#pragma unroll
        for (int k = 0; k < 10; ++k)
            if (k < n) p = fmaf(w[k], x[(size_t)(a + k) * XPAD + d], p);
        grow[2 * STATE + d] = p;
    }
    if (lane == 0) { grow[1100] = (float)n; i1s[s] = a; i2s[s] = b; }
    for (int d = SPAND + lane; d < KP; d += 64) grow[d] = 0.f;
}

// ---------------- span FFNN -> sm scores (fp32, feeds the sort) ----------------
__global__ void k_sm(const float* __restrict__ g, const float* __restrict__ sW1T,
                     const float* __restrict__ sb1, const float* __restrict__ sW2T,
                     const float* __restrict__ sb2, const float* __restrict__ sW3,
                     const float* __restrict__ sb3, float* __restrict__ smo) {
    __shared__ float As[32 * 33];
    __shared__ float Bs[32 * NPADC];
    __shared__ float L1[32 * 161];
    int tid = threadIdx.x;
    int tx = tid & 31, ty = tid >> 5;
    int row0 = blockIdx.x * 32;
    float acc[4][5] = {};
    for (int kb = 0; kb < KP; kb += 32) {
        for (int l = tid; l < 32 * 32; l += 256) {
            int r = l >> 5, cc = l & 31;
            int gr = row0 + r;
            As[r * 33 + cc] = (gr < NSPANS) ? g[(size_t)gr * KP + kb + cc] : 0.f;
        }
        for (int l = tid; l < 32 * NPADC; l += 256) {
            int r = l / NPADC, cc = l - NPADC * r;
            Bs[l] = sW1T[(size_t)(kb + r) * NPADC + cc];
        }
        __syncthreads();
        for (int kk = 0; kk < 32; ++kk) {
            float bv[5];
#pragma unroll
            for (int jn = 0; jn < 5; ++jn) bv[jn] = Bs[kk * NPADC + tx + 32 * jn];
#pragma unroll
            for (int i4 = 0; i4 < 4; ++i4) {
                float av = As[(ty * 4 + i4) * 33 + kk];
#pragma unroll
                for (int jn = 0; jn < 5; ++jn) acc[i4][jn] = fmaf(av, bv[jn], acc[i4][jn]);
            }
        }
        __syncthreads();
    }
#pragma unroll
    for (int i4 = 0; i4 < 4; ++i4)
#pragma unroll
        for (int jn = 0; jn < 5; ++jn) {
            int nn = tx + 32 * jn;
            float v = acc[i4][jn] + (nn < HIDD ? sb1[nn] : 0.f);
            L1[(ty * 4 + i4) * 161 + nn] = fmaxf(v, 0.f);
        }
    __syncthreads();
    float acc2[4][5] = {};
    for (int kk = 0; kk < HIDD; ++kk) {
        float bv[5];
#pragma unroll
        for (int jn = 0; jn < 5; ++jn) bv[jn] = sW2T[(size_t)kk * NPADC + tx + 32 * jn];
#pragma unroll
        for (int i4 = 0; i4 < 4; ++i4) {
            float av = L1[(ty * 4 + i4) * 161 + kk];
#pragma unroll
            for (int jn = 0; jn < 5; ++jn) acc2[i4][jn] = fmaf(av, bv[jn], acc2[i4][jn]);
        }
    }
    float part[4];
#pragma unroll
    for (int i4 = 0; i4 < 4; ++i4) {
        float p = 0.f;
#pragma unroll
        for (int jn = 0; jn < 5; ++jn) {
            int nn = tx + 32 * jn;
            float v = acc2[i4][jn] + (nn < HIDD ? sb2[nn] : 0.f);
            v = fmaxf(v, 0.f);
            p = fmaf(v, (nn < HIDD ? sW3[nn] : 0.f), p);
        }
        part[i4] = p;
    }
    for (int s = 16; s > 0; s >>= 1)
#pragma unroll
        for (int i4 = 0; i4 < 4; ++i4) part[i4] += __shfl_xor(part[i4], s, 32);
    if (tx == 0)
#pragma unroll
        for (int i4 = 0; i4 < 4; ++i4) {
            int gr = row0 + ty * 4 + i4;
            if (gr < NSPANS) smo[gr] = part[i4] + sb3[0];
        }
}

// ---------------- sort + greedy filter + selection ----------------
__global__ __launch_bounds__(1024) void k_sortsel(const float* __restrict__ sm,
                                                  const int* __restrict__ i1s,
                                                  const int* __restrict__ i2s,
                                                  int* __restrict__ selk,
                                                  int* __restrict__ selspan,
                                                  float* __restrict__ smf,
                                                  float* __restrict__ out) {
    __shared__ float ks[SORTN];
    __shared__ unsigned short id16[SORTN];
    __shared__ int ka2[512];
    __shared__ int va2[512];
    int tid = threadIdx.x;
    for (int i = tid; i < SORTN; i += 1024) {
        ks[i] = (i < NSPANS) ? sm[i] : -FLT_MAX;
        id16[i] = (unsigned short)i;
    }
    __syncthreads();
    for (int size = 2; size <= SORTN; size <<= 1) {
        for (int stride = size >> 1; stride > 0; stride >>= 1) {
            for (int t = tid; t < SORTN / 2; t += 1024) {
                int i = ((t & ~(stride - 1)) << 1) | (t & (stride - 1));
                int j = i + stride;
                float ki = ks[i], kj = ks[j];
                unsigned short ai = id16[i], aj = id16[j];
                bool less_ji = (kj > ki) || (kj == ki && aj < ai);
                bool asc = ((i & size) == 0);
                if (less_ji == asc) {
                    ks[i] = kj; ks[j] = ki;
                    id16[i] = aj; id16[j] = ai;
                }
            }
            __syncthreads();
        }
    }
    unsigned* abu = reinterpret_cast<unsigned*>(ks);
    for (int k = tid; k < NSPANS; k += 1024) {
        int sid = id16[k];
        abu[k] = (unsigned)i1s[sid] | ((unsigned)i2s[sid] << 16);
    }
    __syncthreads();
    if (tid < 64) {
        int l = tid;
        unsigned tk = 0;
        int cnt = 0;
        for (int k = 0; k < NSPANS && cnt < NSEL; ++k) {
            unsigned ab = abu[k];
            int a = (int)(ab & 0xFFFFu), b = (int)(ab >> 16);
            int lo = a - (l << 5), hi = b - (l << 5);
            lo = lo < 0 ? 0 : lo;
            hi = hi > 31 ? 31 : hi;
            unsigned m = 0;
            if (hi >= lo) {
                unsigned upper = (hi == 31) ? 0xFFFFFFFFu : ((1u << (hi + 1)) - 1u);
                m = upper & ~((1u << lo) - 1u);
            }
            bool cov = ((tk & m) == m);
            bool all_taken = __all((int)cov);
            int la = a >> 5, lb = b >> 5;
            unsigned long long bal_a = __ballot((int)((l == la) && ((tk >> (a & 31)) & 1u)));
            unsigned long long bal_b = __ballot((int)((l == lb) && ((tk >> (b & 31)) & 1u)));
            bool ok = all_taken || (bal_a == 0ull && bal_b == 0ull);
            if (ok) {
                tk |= m;
                if (l == 0) selk[cnt] = k;
                cnt++;
            }
        }
    }
    __syncthreads();
    if (tid < 512) {
        int r = tid;
        int key = 0x7FFFFFFF;
        if (r < NSEL) {
            int k = selk[r];
            int a = (int)(abu[k] & 0xFFFFu);
            key = (a << 9) | r;
        }
        ka2[r] = key;
        va2[r] = r;
    }
    __syncthreads();
    for (int size = 2; size <= 512; size <<= 1) {
        for (int stride = size >> 1; stride > 0; stride >>= 1) {
            if (tid < 256) {
                int t = tid;
                int i = ((t & ~(stride - 1)) << 1) | (t & (stride - 1));
                int j = i + stride;
                int ki = ka2[i], kj = ka2[j];
                bool asc = ((i & size) == 0);
                if ((kj < ki) == asc) {
                    ka2[i] = kj; ka2[j] = ki;
                    int vi = va2[i]; va2[i] = va2[j]; va2[j] = vi;
                }
            }
            __syncthreads();
        }
    }
    if (tid < NSEL) {
        int r = va2[tid];
        int k = selk[r];
        int sid = id16[k];
        unsigned ab = abu[k];
        selspan[tid] = sid;
        smf[tid] = sm[sid];
        out[NSEL * NSEL + tid] = (float)(ab & 0xFFFFu);
        out[NSEL * NSEL + NSEL + tid] = (float)(ab >> 16);
    }
}

// ---------------- A_i = g_i @ pW1a^T + pb1 ; B_j = g_j @ pW1b^T ----------------
__global__ void k_AB(const float* __restrict__ g, const int* __restrict__ selspan,
                     const float* __restrict__ pW1aT, const float* __restrict__ pW1bT,
                     const float* __restrict__ pb1, float* __restrict__ Aw,
                     float* __restrict__ Bw) {
    __shared__ float grow[KP];
    int r = blockIdx.x, which = blockIdx.y;
    int sid = selspan[r];
    int tid = threadIdx.x;
    for (int d = tid; d < KP; d += 256) grow[d] = g[(size_t)sid * KP + d];
    __syncthreads();
    if (tid < NPADC) {
        const float* WT = which ? pW1bT : pW1aT;
        float acc = 0.f;
        for (int k = 0; k < KP; ++k) acc = fmaf(grow[k], WT[(size_t)k * NPADC + tid], acc);
        if (which == 0) acc += (tid < HIDD ? pb1[tid] : 0.f);
        (which ? Bw : Aw)[(size_t)r * NPADC + tid] = acc;
    }
}

// ---------------- pair FFNN via bf16 MFMA + sij scatter ----------------
__global__ __launch_bounds__(256, 1) void k_pairs_mfma(
    const float* __restrict__ g, const int* __restrict__ selspan,
    const float* __restrict__ smf, const float* __restrict__ Aw,
    const float* __restrict__ Bw, const unsigned short* __restrict__ pw1cb,
    const unsigned short* __restrict__ pw2b, const float* __restrict__ pb2,
    const float* __restrict__ pW3, const float* __restrict__ pb3,
    float* __restrict__ out) {
    int i = blockIdx.x;
    int j0 = blockIdx.y * 32;
    if (j0 >= i) return;
    __shared__ __align__(16) unsigned short Abuf[32][232];
    __shared__ __align__(16) unsigned short Btb[160][232];
    __shared__ __align__(16) unsigned short L1b[32][168];
    __shared__ float BwS[32][160];
    __shared__ float AwS[160];
    __shared__ float GiS[224];
    __shared__ float pb2S[160], pw3S[160];
    __shared__ float parts[4][32];
    int tid = threadIdx.x;
    int lane = tid & 63, wv = tid >> 6;
    int l15 = lane & 15, lg = lane >> 4;
    int sidi = selspan[i];

    if (tid < 160) {
        AwS[tid] = Aw[(size_t)i * NPADC + tid];
        pb2S[tid] = (tid < HIDD) ? pb2[tid] : 0.f;
        pw3S[tid] = (tid < HIDD) ? pW3[tid] : 0.f;
    }
    for (int idx = tid; idx < 32 * 160; idx += 256) {
        int r = idx / 160; int c = idx - r * 160;
        int j = j0 + r;
        BwS[r][c] = Bw[(size_t)(j < i ? j : 0) * NPADC + c];
    }
    mf32x4 acc[2][3];
#pragma unroll
    for (int m = 0; m < 2; ++m)
#pragma unroll
        for (int t = 0; t < 3; ++t) acc[m][t] = (mf32x4){0.f, 0.f, 0.f, 0.f};

    for (int kc = 0; kc < KP; kc += 224) {
        if (tid < 56)
            *(float4*)&GiS[tid * 4] = *(const float4*)&g[(size_t)sidi * KP + kc + tid * 4];
        for (int idx = tid; idx < 160 * 28; idx += 256) {
            int r = idx / 28, s = idx - r * 28;
            uint4 v = *(const uint4*)(pw1cb + (size_t)r * 1120 + kc + s * 8);
            *(uint4*)&Btb[r][s * 8] = v;
        }
        __syncthreads();
        for (int idx = tid; idx < 32 * 56; idx += 256) {
            int r = idx / 56, s = idx - r * 56;
            int j = j0 + r;
            float4 gj = {0.f, 0.f, 0.f, 0.f};
            if (j < i) gj = *(const float4*)&g[(size_t)selspan[j] * KP + kc + s * 4];
            float4 gi = *(const float4*)&GiS[s * 4];
            ushort4 u;
            u.x = f2bf(gj.x * gi.x); u.y = f2bf(gj.y * gi.y);
            u.z = f2bf(gj.z * gi.z); u.w = f2bf(gj.w * gi.w);
            *(ushort4*)&Abuf[r][s * 4] = u;
        }
        __syncthreads();
#pragma unroll
        for (int kk = 0; kk < 7; ++kk) {
            int ko = kk * 32 + lg * 8;
            bf16x8 a0 = *(const bf16x8*)&Abuf[l15][ko];
            bf16x8 a1 = *(const bf16x8*)&Abuf[16 + l15][ko];
#pragma unroll
            for (int t = 0; t < 3; ++t) {
                int n = wv + 4 * t;
                if (n < 10) {
                    bf16x8 bb = *(const bf16x8*)&Btb[n * 16 + l15][ko];
                    acc[0][t] = __builtin_amdgcn_mfma_f32_16x16x32_bf16(a0, bb, acc[0][t], 0, 0, 0);
                    acc[1][t] = __builtin_amdgcn_mfma_f32_16x16x32_bf16(a1, bb, acc[1][t], 0, 0, 0);
                }
            }
        }
        __syncthreads();
    }
#pragma unroll
    for (int m = 0; m < 2; ++m)
#pragma unroll
        for (int t = 0; t < 3; ++t) {
            int n = wv + 4 * t;
            if (n < 10) {
#pragma unroll
                for (int q = 0; q < 4; ++q) {
                    int row = m * 16 + lg * 4 + q;
                    int col = n * 16 + l15;
                    float v = acc[m][t][q] + AwS[col] + BwS[row][col];
                    L1b[row][col] = f2bf(fmaxf(v, 0.f));
                }
            }
        }
    for (int idx = tid; idx < 160 * 20; idx += 256) {
        int r = idx / 20, s = idx - r * 20;
        *(uint4*)&Btb[r][s * 8] = *(const uint4*)(pw2b + (size_t)r * 160 + s * 8);
    }
    __syncthreads();
    mf32x4 acc2[2][3];
#pragma unroll
    for (int m = 0; m < 2; ++m)
#pragma unroll
        for (int t = 0; t < 3; ++t) acc2[m][t] = (mf32x4){0.f, 0.f, 0.f, 0.f};
#pragma unroll
    for (int kk = 0; kk < 5; ++kk) {
        int ko = kk * 32 + lg * 8;
        bf16x8 a0 = *(const bf16x8*)&L1b[l15][ko];
        bf16x8 a1 = *(const bf16x8*)&L1b[16 + l15][ko];
#pragma unroll
        for (int t = 0; t < 3; ++t) {
            int n = wv + 4 * t;
            if (n < 10) {
                bf16x8 bb = *(const bf16x8*)&Btb[n * 16 + l15][ko];
                acc2[0][t] = __builtin_amdgcn_mfma_f32_16x16x32_bf16(a0, bb, acc2[0][t], 0, 0, 0);
                acc2[1][t] = __builtin_amdgcn_mfma_f32_16x16x32_bf16(a1, bb, acc2[1][t], 0, 0, 0);
            }
        }
    }
    float s[2][4] = {};
#pragma unroll
    for (int m = 0; m < 2; ++m)
#pragma unroll
        for (int t = 0; t < 3; ++t) {
            int n = wv + 4 * t;
            if (n < 10) {
#pragma unroll
                for (int q = 0; q < 4; ++q) {
                    int col = n * 16 + l15;
                    float v = fmaxf(acc2[m][t][q] + pb2S[col], 0.f);
                    s[m][q] = fmaf(v, pw3S[col], s[m][q]);
                }
            }
        }
#pragma unroll
    for (int off = 1; off < 16; off <<= 1)
#pragma unroll
        for (int m = 0; m < 2; ++m)
#pragma unroll
            for (int q = 0; q < 4; ++q) s[m][q] += __shfl_xor(s[m][q], off);
    if (l15 == 0) {
#pragma unroll
        for (int m = 0; m < 2; ++m)
#pragma unroll
            for (int q = 0; q < 4; ++q) parts[wv][m * 16 + lg * 4 + q] = s[m][q];
    }
    __syncthreads();
    if (tid < 32) {
        float sa = parts[0][tid] + parts[1][tid] + parts[2][tid] + parts[3][tid];
        int j = j0 + tid;
        if (j < i) out[(size_t)i * NSEL + j] = smf[i] + smf[j] + sa + pb3[0];
    }
}

extern "C" void kernel_launch(void* const* d_in, const int* in_sizes, int n_in,
                              void* d_out, int out_size, void* d_ws, size_t ws_size,
                              hipStream_t stream) {
    (void)in_sizes; (void)n_in; (void)ws_size;
    const int* tokens  = (const int*)d_in[0];
    const float* emb   = (const float*)d_in[1];
    const float* Wih_f = (const float*)d_in[2];
    const float* Whh_f = (const float*)d_in[3];
    const float* b_f   = (const float*)d_in[4];
    const float* Wih_b = (const float*)d_in[5];
    const float* Whh_b = (const float*)d_in[6];
    const float* b_b   = (const float*)d_in[7];
    const float* aW1 = (const float*)d_in[8];  const float* ab1 = (const float*)d_in[9];
    const float* aW2 = (const float*)d_in[10]; const float* ab2 = (const float*)d_in[11];
    const float* aW3 = (const float*)d_in[12]; const float* ab3 = (const float*)d_in[13];
    const float* sW1 = (const float*)d_in[14]; const float* sb1 = (const float*)d_in[15];
    const float* sW2 = (const float*)d_in[16]; const float* sb2 = (const float*)d_in[17];
    const float* sW3 = (const float*)d_in[18]; const float* sb3 = (const float*)d_in[19];
    const float* pW1 = (const float*)d_in[20]; const float* pb1 = (const float*)d_in[21];
    const float* pW2 = (const float*)d_in[22]; const float* pb2 = (const float*)d_in[23];
    const float* pW3 = (const float*)d_in[24]; const float* pb3 = (const float*)d_in[25];
    float* W = (float*)d_ws;
    float* out = (float*)d_out;
    ull* hqL2 = (ull*)(W + OFF_G);
    ull* hqL3 = hqL2 + (size_t)2 * TN * 256;
    int* ctrl = (int*)(hqL3 + (size_t)2 * TN * 256);
    unsigned short* pw1cb = (unsigned short*)(W + OFF_PW1CB);
    unsigned short* pw2b  = (unsigned short*)(W + OFF_PW2B);

    hipMemsetAsync(d_out, 0, (size_t)out_size * sizeof(float), stream);
    hipMemsetAsync(hqL2, 0, (size_t)4 * TN * 256 * sizeof(ull) + 1024, stream);

    k_pre0<<<TN + 2400, 256, 0, stream>>>(tokens, emb, W + OFF_X, Wih_f, Wih_b,
                                          W + OFF_WTF, W + OFF_WTB);
    k_pre1<<<58, 256, 0, stream>>>(aW1, aW2, sW1, sW2, pW1, pW2,
                                   W + OFF_AW1T, W + OFF_AW2T, W + OFF_SW1T, W + OFF_SW2T,
                                   W + OFF_PW1AT, W + OFF_PW1BT, pw1cb, pw2b);
    k_zx<<<dim3(96, 2), 256, 0, stream>>>(W + OFF_X, W + OFF_WTF, W + OFF_WTB, b_f, b_b,
                                          W + OFF_ZXF, W + OFF_ZXB);
    k_lstm_mb8<<<32, 256, 0, stream>>>(W + OFF_ZXF, W + OFF_ZXB, Whh_f, Whh_b, W + OFF_H,
                                       hqL2, hqL3, ctrl);
    k_attn<<<TN, 256, 0, stream>>>(W + OFF_H, W + OFF_AW1T, ab1, W + OFF_AW2T, ab2, aW3, ab3,
                                   W + OFF_ATTN);
    k_spans<<<NSPANS, 64, 0, stream>>>(W + OFF_ATTN, W + OFF_H, W + OFF_X, W + OFF_G,
                                       (int*)(W + OFF_I1), (int*)(W + OFF_I2));
    k_sm<<<(NSPANS + 31) / 32, 256, 0, stream>>>(W + OFF_G, W + OFF_SW1T, sb1, W + OFF_SW2T, sb2,
                                                 sW3, sb3, W + OFF_SM);
    k_sortsel<<<1, 1024, 0, stream>>>(W + OFF_SM, (int*)(W + OFF_I1), (int*)(W + OFF_I2),
                                      (int*)(W + OFF_SELK), (int*)(W + OFF_SELSPAN),
                                      W + OFF_SMF, out);
    k_AB<<<dim3(NSEL, 2), 256, 0, stream>>>(W + OFF_G, (int*)(W + OFF_SELSPAN), W + OFF_PW1AT,
                                            W + OFF_PW1BT, pb1, W + OFF_A, W + OFF_B);
    k_pairs_mfma<<<dim3(NSEL, 10), 256, 0, stream>>>(W + OFF_G, (int*)(W + OFF_SELSPAN),
                                                     W + OFF_SMF, W + OFF_A, W + OFF_B,
                                                     pw1cb, pw2b, pb2, pW3, pb3, out);
}

// Round 15
// 2213.082 us; speedup vs baseline: 1.3488x; 1.3488x over previous
//
#include <hip/hip_runtime.h>
#include <hip/hip_bf16.h>
#include <math.h>
#include <float.h>

#define TN      768
#define EMBD    300
#define XPAD    304
#define LSTMD   200
#define G4      800
#define STATE   400
#define HIDD    150
#define NPADC   160
#define SPAND   1101
#define KP      1120
#define NSPANS  7635
#define NSEL    307
#define SORTN   8192

typedef unsigned long long ull;
typedef __attribute__((ext_vector_type(8))) short bf16x8;
typedef __attribute__((ext_vector_type(4))) float mf32x4;

// ---- workspace offsets (in floats) ----
#define OFF_X       0u
#define OFF_ZXF     233472u
#define OFF_ZXB     847872u
#define OFF_H       1462272u
#define OFF_ATTN    1769472u
#define OFF_I1      1770496u
#define OFF_I2      1778176u
#define OFF_SM      1785856u
#define OFF_SELK    1793536u
#define OFF_SELSPAN 1794048u
#define OFF_SMF     1794560u
#define OFF_A       1795072u
#define OFF_B       1844224u
#define OFF_WTF     1893376u
#define OFF_WTB     2133376u
#define OFF_AW1T    2373376u
#define OFF_AW2T    2437376u
#define OFF_SW1T    2461376u
#define OFF_SW2T    2640576u
#define OFF_PW1AT   2664576u
#define OFF_PW1BT   2843776u
#define OFF_G       3226176u
#define OFF_PW1CB   11777376u   /* bf16 [160][1120] = 89600 floats */
#define OFF_PW2B    11866976u   /* bf16 [160][160]  = 12800 floats */
// hqL2 + hqL3 mailboxes + ctrl alias the head of the G region (k_spans
// overwrites g rows strictly after the LSTM in stream order).

#define REP50(M) M(0) M(1) M(2) M(3) M(4) M(5) M(6) M(7) M(8) M(9) \
 M(10) M(11) M(12) M(13) M(14) M(15) M(16) M(17) M(18) M(19) \
 M(20) M(21) M(22) M(23) M(24) M(25) M(26) M(27) M(28) M(29) \
 M(30) M(31) M(32) M(33) M(34) M(35) M(36) M(37) M(38) M(39) \
 M(40) M(41) M(42) M(43) M(44) M(45) M(46) M(47) M(48) M(49)

__device__ __forceinline__ float sigf(float x) { return 1.f / (1.f + __expf(-x)); }
__device__ __forceinline__ float tanhf_(float x) {
    x = fminf(15.f, fmaxf(-15.f, x));
    float e = __expf(2.f * x);
    return (e - 1.f) / (e + 1.f);
}
__device__ __forceinline__ unsigned short f2bf(float v) {
    __hip_bfloat16 h = __float2bfloat16(v);
    return *(unsigned short*)&h;
}
// LDS-only barrier: syncs waves + drains LDS ops, but lets global loads/stores
// stay in flight (no vmcnt(0) drain that __syncthreads would emit).
__device__ __forceinline__ void lds_barrier() {
    asm volatile("s_waitcnt lgkmcnt(0)" ::: "memory");
    __builtin_amdgcn_s_barrier();
    __builtin_amdgcn_sched_barrier(0);
}

// ---------------- fused gather + Wih transposes (sequential, pre-LSTM) -----
__global__ void k_pre0(const int* __restrict__ tokens, const float* __restrict__ emb,
                       float* __restrict__ x, const float* __restrict__ Wih_f,
                       const float* __restrict__ Wih_b, float* __restrict__ wtf,
                       float* __restrict__ wtb) {
    int b = blockIdx.x, tid = threadIdx.x;
    if (b < TN) {
        int tok = tokens[b];
        for (int d = tid; d < XPAD; d += 256)
            x[b * XPAD + d] = (d < EMBD) ? emb[(size_t)tok * EMBD + d] : 0.f;
    } else if (b < TN + 1200) {
        int bb = b - TN;
        int k = bb >> 2, n = ((bb & 3) << 8) + tid;
        if (n < G4) wtf[(size_t)k * G4 + n] = Wih_f[(size_t)n * EMBD + k];
    } else {
        int bb = b - TN - 1200;
        int k = bb >> 2, n = ((bb & 3) << 8) + tid;
        if (n < G4) wtb[(size_t)k * G4 + n] = Wih_b[(size_t)n * EMBD + k];
    }
}

// ---------------- fused small-weight prep (sequential, pre-LSTM) ----------
__device__ void prep_tr(const float* __restrict__ src, float* __restrict__ dst,
                        int N, int K, int stride, int off, int Npad, int totalK,
                        int part, int nparts, int tid) {
    int total = totalK * Npad;
    for (int idx = part * 256 + tid; idx < total; idx += nparts * 256) {
        int k = idx / Npad, n = idx - k * Npad;
        dst[idx] = (k < K && n < N) ? src[(size_t)n * stride + off + k] : 0.f;
    }
}
__device__ void prep_bf(const float* __restrict__ src, unsigned short* __restrict__ dst,
                        int R, int C, int stride, int off, int NR, int NC,
                        int part, int nparts, int tid) {
    int total = NR * NC;
    for (int idx = part * 256 + tid; idx < total; idx += nparts * 256) {
        int r = idx / NC, c = idx - r * NC;
        float v = (r < R && c < C) ? src[(size_t)r * stride + off + c] : 0.f;
        dst[idx] = f2bf(v);
    }
}
__global__ void k_pre1(const float* __restrict__ aW1, const float* __restrict__ aW2,
                       const float* __restrict__ sW1, const float* __restrict__ sW2,
                       const float* __restrict__ pW1, const float* __restrict__ pW2,
                       float* __restrict__ aW1T, float* __restrict__ aW2T,
                       float* __restrict__ sW1T, float* __restrict__ sW2T,
                       float* __restrict__ pW1AT, float* __restrict__ pW1BT,
                       unsigned short* __restrict__ pw1cb,
                       unsigned short* __restrict__ pw2b) {
    int p = blockIdx.x, tid = threadIdx.x;
    if (p < 4)       prep_tr(aW1, aW1T, 150, 400, 400, 0, 160, 400, p, 4, tid);
    else if (p < 6)  prep_tr(aW2, aW2T, 150, 150, 150, 0, 160, 150, p - 4, 2, tid);
    else if (p < 18) prep_tr(sW1, sW1T, 150, SPAND, SPAND, 0, 160, KP, p - 6, 12, tid);
    else if (p < 20) prep_tr(sW2, sW2T, 150, 150, 150, 0, 160, 150, p - 18, 2, tid);
    else if (p < 32) prep_tr(pW1, pW1AT, 150, SPAND, 3303, 0, 160, KP, p - 20, 12, tid);
    else if (p < 44) prep_tr(pW1, pW1BT, 150, SPAND, 3303, 1101, 160, KP, p - 32, 12, tid);
    else if (p < 56) prep_bf(pW1, pw1cb, 150, SPAND, 3303, 2202, 160, KP, p - 44, 12, tid);
    else             prep_bf(pW2, pw2b, 150, 150, 150, 0, 160, 160, p - 56, 2, tid);
}

// ---------------- input projections zx = x @ Wih^T + b ----------------
__global__ void k_zx(const float* __restrict__ x, const float* __restrict__ WTf,
                     const float* __restrict__ WTb, const float* __restrict__ bf,
                     const float* __restrict__ bb, float* __restrict__ zxf,
                     float* __restrict__ zxb) {
    __shared__ float xl[8 * XPAD];
    int tid = threadIdx.x;
    int bm = blockIdx.x, dir = blockIdx.y;
    for (int l = tid; l < 8 * XPAD; l += 256) xl[l] = x[(size_t)(bm * 8) * XPAD + l];
    __syncthreads();
    const float* WT = dir ? WTb : WTf;
    const float* bv = dir ? bb : bf;
    float* zx = dir ? zxb : zxf;
    for (int jj = 0; jj < 4; ++jj) {
        int n = tid + 256 * jj;
        if (n >= G4) break;
        float acc[8] = {0, 0, 0, 0, 0, 0, 0, 0};
        for (int k = 0; k < EMBD; ++k) {
            float wv = WT[(size_t)k * G4 + n];
#pragma unroll
            for (int r = 0; r < 8; ++r) acc[r] = fmaf(xl[r * XPAD + k], wv, acc[r]);
        }
        float bias = bv[n];
#pragma unroll
        for (int r = 0; r < 8; ++r) {
            int row = bm * 8 + r;
            int trow = dir ? (TN - 1 - row) : row;
            zx[(size_t)trow * G4 + n] = acc[r] + bias;
        }
    }
}

// ---------------- BiLSTM: R12 base + LDS-only in-loop barriers -------------
// ONLY change vs R12 (1370us, VGPR 128): the two in-loop __syncthreads are
// replaced with lds_barrier() (s_waitcnt lgkmcnt(0) + raw s_barrier). The
// within-block sync only needs LDS (zl/hprev) visibility; __syncthreads'
// implicit vmcnt(0) drain forced every step's barrier to also wait for the
// zx HBM load (~900cyc, partially exposed) and the hcat global store. With
// LDS-only barriers those retire in the background (zx waited only at its
// use next step; hcat at kernel end). Dot stays single-accumulator (R14
// proved splitting it destroys the AGPR weight allocation).
__global__ __launch_bounds__(256, 1) void k_lstm_mb8(const float* __restrict__ zxf,
                                                     const float* __restrict__ zxb,
                                                     const float* __restrict__ Whh_f,
                                                     const float* __restrict__ Whh_b,
                                                     float* __restrict__ hcat,
                                                     ull* __restrict__ hqL2,
                                                     ull* __restrict__ hqL3,
                                                     int* __restrict__ ctrl) {
    int blk = blockIdx.x;
    int lane8 = blk & 7;
    if (lane8 >= 2) return;
    int dir = lane8, b = blk >> 3;
    int tid = threadIdx.x;
    __shared__ int s_mode;
    if (tid == 0) {
        unsigned xcc;
        asm volatile("s_getreg_b32 %0, hwreg(HW_REG_XCC_ID)" : "=s"(xcc));
        xcc &= 7u;
        __hip_atomic_store(&ctrl[dir * 4 + b], (int)(1u + xcc), __ATOMIC_RELAXED,
                           __HIP_MEMORY_SCOPE_AGENT);
        int v0, v1, v2, v3;
        do {
            v0 = __hip_atomic_load(&ctrl[dir * 4 + 0], __ATOMIC_RELAXED,
                                   __HIP_MEMORY_SCOPE_AGENT);
            v1 = __hip_atomic_load(&ctrl[dir * 4 + 1], __ATOMIC_RELAXED,
                                   __HIP_MEMORY_SCOPE_AGENT);
            v2 = __hip_atomic_load(&ctrl[dir * 4 + 2], __ATOMIC_RELAXED,
                                   __HIP_MEMORY_SCOPE_AGENT);
            v3 = __hip_atomic_load(&ctrl[dir * 4 + 3], __ATOMIC_RELAXED,
                                   __HIP_MEMORY_SCOPE_AGENT);
        } while (!v0 || !v1 || !v2 || !v3);
        s_mode = (v0 == v1 && v1 == v2 && v2 == v3) ? 1 : 0;
    }
    __syncthreads();
    int mode = s_mode;  // 1 = XCD-local L2 exchange; 0 = L3 (R4 path)

    const float* zx = dir ? zxb : zxf;
    const float* Whh = dir ? Whh_b : Whh_f;
    ull* hq2d = hqL2 + (size_t)dir * TN * 256;
    ull* hq3d = hqL3 + (size_t)dir * TN * 256;
    __shared__ __align__(16) float hprev[LSTMD];
    __shared__ float zl[200];
    bool active = tid < 200;
    int q = tid / 50, u = tid % 50;
    int gr_row = q * 200 + b * 50 + u;
    int grs = active ? gr_row : 0;
    const float4* wr = (const float4*)(Whh + (size_t)grs * LSTMD);
#define WDECL(i) float4 w##i = wr[i];
    REP50(WDECL)
#undef WDECL
    float c = 0.f;
    for (int l = tid; l < LSTMD; l += 256) hprev[l] = 0.f;
    int remote_idx = (tid < b * 50) ? tid : tid + 50;
    __syncthreads();
    float zpre = zx[grs];
    for (int t = 0; t < TN; ++t) {
        float acc = zpre;
        const float4* h4 = (const float4*)hprev;
#define WFMA(i) { float4 hv = h4[i]; \
        acc = fmaf(w##i.x, hv.x, acc); acc = fmaf(w##i.y, hv.y, acc); \
        acc = fmaf(w##i.z, hv.z, acc); acc = fmaf(w##i.w, hv.w, acc); }
        REP50(WFMA)
#undef WFMA
        if (active) zl[tid] = acc;
        lds_barrier();
        int trow = dir ? (TN - 1 - t) : t;
        if (tid < 50) {
            float zi = zl[tid], zf = zl[50 + tid], zg = zl[100 + tid], zo = zl[150 + tid];
            c = sigf(zf) * c + sigf(zi) * tanhf_(zg);
            float h = sigf(zo) * tanhf_(c);
            hcat[(size_t)trow * STATE + dir * LSTMD + b * 50 + tid] = h;
            hprev[b * 50 + tid] = h;
            if (t + 1 < TN) {
                ull pk = (ull)__float_as_uint(h) | ((ull)(unsigned)(t + 1) << 32);
                size_t slot = (size_t)t * 256 + b * 50 + tid;
                if (mode) {
                    (void)__hip_atomic_exchange(&hq2d[slot], pk, __ATOMIC_RELAXED,
                                                __HIP_MEMORY_SCOPE_WORKGROUP);
                } else {
                    __hip_atomic_store(&hq3d[slot], pk, __ATOMIC_RELAXED,
                                       __HIP_MEMORY_SCOPE_AGENT);
                }
            }
        }
        if (t + 1 < TN) {
            zpre = zx[(size_t)(t + 1) * G4 + grs];  // stays in flight across barrier
            if (tid < 150) {
                size_t slot = (size_t)t * 256 + remote_idx;
                ull v;
                if (mode) {
                    for (;;) {
                        ull probe = ~0ull;  // impossible tag: CAS fails, returns
                                            // current value — guaranteed L2 RMW
                        __hip_atomic_compare_exchange_strong(
                            &hq2d[slot], &probe, ~0ull, __ATOMIC_RELAXED,
                            __ATOMIC_RELAXED, __HIP_MEMORY_SCOPE_WORKGROUP);
                        if ((unsigned)(probe >> 32) == (unsigned)(t + 1)) {
                            v = probe; break;
                        }
                    }
                } else {
                    do {
                        v = __hip_atomic_load(&hq3d[slot], __ATOMIC_RELAXED,
                                              __HIP_MEMORY_SCOPE_AGENT);
                    } while ((unsigned)(v >> 32) != (unsigned)(t + 1));
                }
                hprev[remote_idx] = __uint_as_float((unsigned)v);
            }
            lds_barrier();
        }
    }
}

// ---------------- attention FFNN: per-token scalar ----------------
__global__ void k_attn(const float* __restrict__ hcat, const float* __restrict__ aW1T,
                       const float* __restrict__ ab1, const float* __restrict__ aW2T,
                       const float* __restrict__ ab2, const float* __restrict__ aW3,
                       const float* __restrict__ ab3, float* __restrict__ attn) {
    __shared__ float hrow[STATE];
    __shared__ float l1[NPADC];
    __shared__ float l2[NPADC];
    __shared__ float red[256];
    int t = blockIdx.x, tid = threadIdx.x;
    for (int d = tid; d < STATE; d += 256) hrow[d] = hcat[(size_t)t * STATE + d];
    __syncthreads();
    if (tid < HIDD) {
        float acc = ab1[tid];
        for (int k = 0; k < STATE; ++k) acc = fmaf(hrow[k], aW1T[(size_t)k * NPADC + tid], acc);
        l1[tid] = fmaxf(acc, 0.f);
    }
    __syncthreads();
    if (tid < HIDD) {
        float acc = ab2[tid];
        for (int k = 0; k < HIDD; ++k) acc = fmaf(l1[k], aW2T[(size_t)k * NPADC + tid], acc);
        l2[tid] = fmaxf(acc, 0.f);
    }
    __syncthreads();
    float partial = (tid < HIDD) ? l2[tid] * aW3[tid] : 0.f;
    red[tid] = partial;
    __syncthreads();
    for (int s = 128; s > 0; s >>= 1) {
        if (tid < s) red[tid] += red[tid + s];
        __syncthreads();
    }
    if (tid == 0) attn[t] = red[0] + ab3[0];
}

// ---------------- span construction: g rows + i1/i2 ----------------
__global__ void k_spans(const float* __restrict__ attn, const float* __restrict__ hcat,
                        const float* __restrict__ x, float* __restrict__ g,
                        int* __restrict__ i1s, int* __restrict__ i2s) {
    int s = blockIdx.x;
    int n = 1, base = 0;
    while (s >= base + (TN - n + 1)) { base += TN - n + 1; n++; }
    int a = s - base, b = a + n - 1;
    int lane = threadIdx.x;
    float e[10];
    float mx = -FLT_MAX;
#pragma unroll
    for (int k = 0; k < 10; ++k)
        if (k < n) { e[k] = attn[a + k]; mx = fmaxf(mx, e[k]); }
    float ssum = 0.f;
#pragma unroll
    for (int k = 0; k < 10; ++k)
        if (k < n) { e[k] = __expf(e[k] - mx); ssum += e[k]; }
    float w[10];
#pragma unroll
    for (int k = 0; k < 10; ++k) w[k] = (k < n) ? e[k] / ssum : 0.f;

    float* grow = g + (size_t)s * KP;
    for (int d = lane; d < STATE; d += 64) grow[d] = hcat[(size_t)a * STATE + d];
    for (int d = lane; d < STATE; d += 64) grow[STATE + d] = hcat[(size_t)b * STATE + d];
    for (int d = lane; d < EMBD; d += 64) {
        float p = 0.f;
#pragma unroll
        for (int k = 0; k < 10; ++k)
            if (k < n) p = fmaf(w[k], x[(size_t)(a + k) * XPAD + d], p);
        grow[2 * STATE + d] = p;
    }
    if (lane == 0) { grow[1100] = (float)n; i1s[s] = a; i2s[s] = b; }
    for (int d = SPAND + lane; d < KP; d += 64) grow[d] = 0.f;
}

// ---------------- span FFNN -> sm scores (fp32, feeds the sort) ----------------
__global__ void k_sm(const float* __restrict__ g, const float* __restrict__ sW1T,
                     const float* __restrict__ sb1, const float* __restrict__ sW2T,
                     const float* __restrict__ sb2, const float* __restrict__ sW3,
                     const float* __restrict__ sb3, float* __restrict__ smo) {
    __shared__ float As[32 * 33];
    __shared__ float Bs[32 * NPADC];
    __shared__ float L1[32 * 161];
    int tid = threadIdx.x;
    int tx = tid & 31, ty = tid >> 5;
    int row0 = blockIdx.x * 32;
    float acc[4][5] = {};
    for (int kb = 0; kb < KP; kb += 32) {
        for (int l = tid; l < 32 * 32; l += 256) {
            int r = l >> 5, cc = l & 31;
            int gr = row0 + r;
            As[r * 33 + cc] = (gr < NSPANS) ? g[(size_t)gr * KP + kb + cc] : 0.f;
        }
        for (int l = tid; l < 32 * NPADC; l += 256) {
            int r = l / NPADC, cc = l - NPADC * r;
            Bs[l] = sW1T[(size_t)(kb + r) * NPADC + cc];
        }
        __syncthreads();
        for (int kk = 0; kk < 32; ++kk) {
            float bv[5];
#pragma unroll
            for (int jn = 0; jn < 5; ++jn) bv[jn] = Bs[kk * NPADC + tx + 32 * jn];
#pragma unroll
            for (int i4 = 0; i4 < 4; ++i4) {
                float av = As[(ty * 4 + i4) * 33 + kk];
#pragma unroll
                for (int jn = 0; jn < 5; ++jn) acc[i4][jn] = fmaf(av, bv[jn], acc[i4][jn]);
            }
        }
        __syncthreads();
    }
#pragma unroll
    for (int i4 = 0; i4 < 4; ++i4)
#pragma unroll
        for (int jn = 0; jn < 5; ++jn) {
            int nn = tx + 32 * jn;
            float v = acc[i4][jn] + (nn < HIDD ? sb1[nn] : 0.f);
            L1[(ty * 4 + i4) * 161 + nn] = fmaxf(v, 0.f);
        }
    __syncthreads();
    float acc2[4][5] = {};
    for (int kk = 0; kk < HIDD; ++kk) {
        float bv[5];
#pragma unroll
        for (int jn = 0; jn < 5; ++jn) bv[jn] = sW2T[(size_t)kk * NPADC + tx + 32 * jn];
#pragma unroll
        for (int i4 = 0; i4 < 4; ++i4) {
            float av = L1[(ty * 4 + i4) * 161 + kk];
#pragma unroll
            for (int jn = 0; jn < 5; ++jn) acc2[i4][jn] = fmaf(av, bv[jn], acc2[i4][jn]);
        }
    }
    float part[4];
#pragma unroll
    for (int i4 = 0; i4 < 4; ++i4) {
        float p = 0.f;
#pragma unroll
        for (int jn = 0; jn < 5; ++jn) {
            int nn = tx + 32 * jn;
            float v = acc2[i4][jn] + (nn < HIDD ? sb2[nn] : 0.f);
            v = fmaxf(v, 0.f);
            p = fmaf(v, (nn < HIDD ? sW3[nn] : 0.f), p);
        }
        part[i4] = p;
    }
    for (int s = 16; s > 0; s >>= 1)
#pragma unroll
        for (int i4 = 0; i4 < 4; ++i4) part[i4] += __shfl_xor(part[i4], s, 32);
    if (tx == 0)
#pragma unroll
        for (int i4 = 0; i4 < 4; ++i4) {
            int gr = row0 + ty * 4 + i4;
            if (gr < NSPANS) smo[gr] = part[i4] + sb3[0];
        }
}

// ---------------- sort + greedy filter + selection ----------------
__global__ __launch_bounds__(1024) void k_sortsel(const float* __restrict__ sm,
                                                  const int* __restrict__ i1s,
                                                  const int* __restrict__ i2s,
                                                  int* __restrict__ selk,
                                                  int* __restrict__ selspan,
                                                  float* __restrict__ smf,
                                                  float* __restrict__ out) {
    __shared__ float ks[SORTN];
    __shared__ unsigned short id16[SORTN];
    __shared__ int ka2[512];
    __shared__ int va2[512];
    int tid = threadIdx.x;
    for (int i = tid; i < SORTN; i += 1024) {
        ks[i] = (i < NSPANS) ? sm[i] : -FLT_MAX;
        id16[i] = (unsigned short)i;
    }
    __syncthreads();
    for (int size = 2; size <= SORTN; size <<= 1) {
        for (int stride = size >> 1; stride > 0; stride >>= 1) {
            for (int t = tid; t < SORTN / 2; t += 1024) {
                int i = ((t & ~(stride - 1)) << 1) | (t & (stride - 1));
                int j = i + stride;
                float ki = ks[i], kj = ks[j];
                unsigned short ai = id16[i], aj = id16[j];
                bool less_ji = (kj > ki) || (kj == ki && aj < ai);
                bool asc = ((i & size) == 0);
                if (less_ji == asc) {
                    ks[i] = kj; ks[j] = ki;
                    id16[i] = aj; id16[j] = ai;
                }
            }
            __syncthreads();
        }
    }
    unsigned* abu = reinterpret_cast<unsigned*>(ks);
    for (int k = tid; k < NSPANS; k += 1024) {
        int sid = id16[k];
        abu[k] = (unsigned)i1s[sid] | ((unsigned)i2s[sid] << 16);
    }
    __syncthreads();
    if (tid < 64) {
        int l = tid;
        unsigned tk = 0;
        int cnt = 0;
        for (int k = 0; k < NSPANS && cnt < NSEL; ++k) {
            unsigned ab = abu[k];
            int a = (int)(ab & 0xFFFFu), b = (int)(ab >> 16);
            int lo = a - (l << 5), hi = b - (l << 5);
            lo = lo < 0 ? 0 : lo;
            hi = hi > 31 ? 31 : hi;
            unsigned m = 0;
            if (hi >= lo) {
                unsigned upper = (hi == 31) ? 0xFFFFFFFFu : ((1u << (hi + 1)) - 1u);
                m = upper & ~((1u << lo) - 1u);
            }
            bool cov = ((tk & m) == m);
            bool all_taken = __all((int)cov);
            int la = a >> 5, lb = b >> 5;
            unsigned long long bal_a = __ballot((int)((l == la) && ((tk >> (a & 31)) & 1u)));
            unsigned long long bal_b = __ballot((int)((l == lb) && ((tk >> (b & 31)) & 1u)));
            bool ok = all_taken || (bal_a == 0ull && bal_b == 0ull);
            if (ok) {
                tk |= m;
                if (l == 0) selk[cnt] = k;
                cnt++;
            }
        }
    }
    __syncthreads();
    if (tid < 512) {
        int r = tid;
        int key = 0x7FFFFFFF;
        if (r < NSEL) {
            int k = selk[r];
            int a = (int)(abu[k] & 0xFFFFu);
            key = (a << 9) | r;
        }
        ka2[r] = key;
        va2[r] = r;
    }
    __syncthreads();
    for (int size = 2; size <= 512; size <<= 1) {
        for (int stride = size >> 1; stride > 0; stride >>= 1) {
            if (tid < 256) {
                int t = tid;
                int i = ((t & ~(stride - 1)) << 1) | (t & (stride - 1));
                int j = i + stride;
                int ki = ka2[i], kj = ka2[j];
                bool asc = ((i & size) == 0);
                if ((kj < ki) == asc) {
                    ka2[i] = kj; ka2[j] = ki;
                    int vi = va2[i]; va2[i] = va2[j]; va2[j] = vi;
                }
            }
            __syncthreads();
        }
    }
    if (tid < NSEL) {
        int r = va2[tid];
        int k = selk[r];
        int sid = id16[k];
        unsigned ab = abu[k];
        selspan[tid] = sid;
        smf[tid] = sm[sid];
        out[NSEL * NSEL + tid] = (float)(ab & 0xFFFFu);
        out[NSEL * NSEL + NSEL + tid] = (float)(ab >> 16);
    }
}

// ---------------- A_i = g_i @ pW1a^T + pb1 ; B_j = g_j @ pW1b^T ----------------
__global__ void k_AB(const float* __restrict__ g, const int* __restrict__ selspan,
                     const float* __restrict__ pW1aT, const float* __restrict__ pW1bT,
                     const float* __restrict__ pb1, float* __restrict__ Aw,
                     float* __restrict__ Bw) {
    __shared__ float grow[KP];
    int r = blockIdx.x, which = blockIdx.y;
    int sid = selspan[r];
    int tid = threadIdx.x;
    for (int d = tid; d < KP; d += 256) grow[d] = g[(size_t)sid * KP + d];
    __syncthreads();
    if (tid < NPADC) {
        const float* WT = which ? pW1bT : pW1aT;
        float acc = 0.f;
        for (int k = 0; k < KP; ++k) acc = fmaf(grow[k], WT[(size_t)k * NPADC + tid], acc);
        if (which == 0) acc += (tid < HIDD ? pb1[tid] : 0.f);
        (which ? Bw : Aw)[(size_t)r * NPADC + tid] = acc;
    }
}

// ---------------- pair FFNN via bf16 MFMA + sij scatter ----------------
__global__ __launch_bounds__(256, 1) void k_pairs_mfma(
    const float* __restrict__ g, const int* __restrict__ selspan,
    const float* __restrict__ smf, const float* __restrict__ Aw,
    const float* __restrict__ Bw, const unsigned short* __restrict__ pw1cb,
    const unsigned short* __restrict__ pw2b, const float* __restrict__ pb2,
    const float* __restrict__ pW3, const float* __restrict__ pb3,
    float* __restrict__ out) {
    int i = blockIdx.x;
    int j0 = blockIdx.y * 32;
    if (j0 >= i) return;
    __shared__ __align__(16) unsigned short Abuf[32][232];
    __shared__ __align__(16) unsigned short Btb[160][232];
    __shared__ __align__(16) unsigned short L1b[32][168];
    __shared__ float BwS[32][160];
    __shared__ float AwS[160];
    __shared__ float GiS[224];
    __shared__ float pb2S[160], pw3S[160];
    __shared__ float parts[4][32];
    int tid = threadIdx.x;
    int lane = tid & 63, wv = tid >> 6;
    int l15 = lane & 15, lg = lane >> 4;
    int sidi = selspan[i];

    if (tid < 160) {
        AwS[tid] = Aw[(size_t)i * NPADC + tid];
        pb2S[tid] = (tid < HIDD) ? pb2[tid] : 0.f;
        pw3S[tid] = (tid < HIDD) ? pW3[tid] : 0.f;
    }
    for (int idx = tid; idx < 32 * 160; idx += 256) {
        int r = idx / 160; int c = idx - r * 160;
        int j = j0 + r;
        BwS[r][c] = Bw[(size_t)(j < i ? j : 0) * NPADC + c];
    }
    mf32x4 acc[2][3];
#pragma unroll
    for (int m = 0; m < 2; ++m)
#pragma unroll
        for (int t = 0; t < 3; ++t) acc[m][t] = (mf32x4){0.f, 0.f, 0.f, 0.f};

    for (int kc = 0; kc < KP; kc += 224) {
        if (tid < 56)
            *(float4*)&GiS[tid * 4] = *(const float4*)&g[(size_t)sidi * KP + kc + tid * 4];
        for (int idx = tid; idx < 160 * 28; idx += 256) {
            int r = idx / 28, s = idx - r * 28;
            uint4 v = *(const uint4*)(pw1cb + (size_t)r * 1120 + kc + s * 8);
            *(uint4*)&Btb[r][s * 8] = v;
        }
        __syncthreads();
        for (int idx = tid; idx < 32 * 56; idx += 256) {
            int r = idx / 56, s = idx - r * 56;
            int j = j0 + r;
            float4 gj = {0.f, 0.f, 0.f, 0.f};
            if (j < i) gj = *(const float4*)&g[(size_t)selspan[j] * KP + kc + s * 4];
            float4 gi = *(const float4*)&GiS[s * 4];
            ushort4 u;
            u.x = f2bf(gj.x * gi.x); u.y = f2bf(gj.y * gi.y);
            u.z = f2bf(gj.z * gi.z); u.w = f2bf(gj.w * gi.w);
            *(ushort4*)&Abuf[r][s * 4] = u;
        }
        __syncthreads();
#pragma unroll
        for (int kk = 0; kk < 7; ++kk) {
            int ko = kk * 32 + lg * 8;
            bf16x8 a0 = *(const bf16x8*)&Abuf[l15][ko];
            bf16x8 a1 = *(const bf16x8*)&Abuf[16 + l15][ko];
#pragma unroll
            for (int t = 0; t < 3; ++t) {
                int n = wv + 4 * t;
                if (n < 10) {
                    bf16x8 bb = *(const bf16x8*)&Btb[n * 16 + l15][ko];
                    acc[0][t] = __builtin_amdgcn_mfma_f32_16x16x32_bf16(a0, bb, acc[0][t], 0, 0, 0);
                    acc[1][t] = __builtin_amdgcn_mfma_f32_16x16x32_bf16(a1, bb, acc[1][t], 0, 0, 0);
                }
            }
        }
        __syncthreads();
    }
#pragma unroll
    for (int m = 0; m < 2; ++m)
#pragma unroll
        for (int t = 0; t < 3; ++t) {
            int n = wv + 4 * t;
            if (n < 10) {
#pragma unroll
                for (int q = 0; q < 4; ++q) {
                    int row = m * 16 + lg * 4 + q;
                    int col = n * 16 + l15;
                    float v = acc[m][t][q] + AwS[col] + BwS[row][col];
                    L1b[row][col] = f2bf(fmaxf(v, 0.f));
                }
            }
        }
    for (int idx = tid; idx < 160 * 20; idx += 256) {
        int r = idx / 20, s = idx - r * 20;
        *(uint4*)&Btb[r][s * 8] = *(const uint4*)(pw2b + (size_t)r * 160 + s * 8);
    }
    __syncthreads();
    mf32x4 acc2[2][3];
#pragma unroll
    for (int m = 0; m < 2; ++m)
#pragma unroll
        for (int t = 0; t < 3; ++t) acc2[m][t] = (mf32x4){0.f, 0.f, 0.f, 0.f};
#pragma unroll
    for (int kk = 0; kk < 5; ++kk) {
        int ko = kk * 32 + lg * 8;
        bf16x8 a0 = *(const bf16x8*)&L1b[l15][ko];
        bf16x8 a1 = *(const bf16x8*)&L1b[16 + l15][ko];
#pragma unroll
        for (int t = 0; t < 3; ++t) {
            int n = wv + 4 * t;
            if (n < 10) {
                bf16x8 bb = *(const bf16x8*)&Btb[n * 16 + l15][ko];
                acc2[0][t] = __builtin_amdgcn_mfma_f32_16x16x32_bf16(a0, bb, acc2[0][t], 0, 0, 0);
                acc2[1][t] = __builtin_amdgcn_mfma_f32_16x16x32_bf16(a1, bb, acc2[1][t], 0, 0, 0);
            }
        }
    }
    float s[2][4] = {};
#pragma unroll
    for (int m = 0; m < 2; ++m)
#pragma unroll
        for (int t = 0; t < 3; ++t) {
            int n = wv + 4 * t;
            if (n < 10) {
#pragma unroll
                for (int q = 0; q < 4; ++q) {
                    int col = n * 16 + l15;
                    float v = fmaxf(acc2[m][t][q] + pb2S[col], 0.f);
                    s[m][q] = fmaf(v, pw3S[col], s[m][q]);
                }
            }
        }
#pragma unroll
    for (int off = 1; off < 16; off <<= 1)
#pragma unroll
        for (int m = 0; m < 2; ++m)
#pragma unroll
            for (int q = 0; q < 4; ++q) s[m][q] += __shfl_xor(s[m][q], off);
    if (l15 == 0) {
#pragma unroll
        for (int m = 0; m < 2; ++m)
#pragma unroll
            for (int q = 0; q < 4; ++q) parts[wv][m * 16 + lg * 4 + q] = s[m][q];
    }
    __syncthreads();
    if (tid < 32) {
        float sa = parts[0][tid] + parts[1][tid] + parts[2][tid] + parts[3][tid];
        int j = j0 + tid;
        if (j < i) out[(size_t)i * NSEL + j] = smf[i] + smf[j] + sa + pb3[0];
    }
}

extern "C" void kernel_launch(void* const* d_in, const int* in_sizes, int n_in,
                              void* d_out, int out_size, void* d_ws, size_t ws_size,
                              hipStream_t stream) {
    (void)in_sizes; (void)n_in; (void)ws_size;
    const int* tokens  = (const int*)d_in[0];
    const float* emb   = (const float*)d_in[1];
    const float* Wih_f = (const float*)d_in[2];
    const float* Whh_f = (const float*)d_in[3];
    const float* b_f   = (const float*)d_in[4];
    const float* Wih_b = (const float*)d_in[5];
    const float* Whh_b = (const float*)d_in[6];
    const float* b_b   = (const float*)d_in[7];
    const float* aW1 = (const float*)d_in[8];  const float* ab1 = (const float*)d_in[9];
    const float* aW2 = (const float*)d_in[10]; const float* ab2 = (const float*)d_in[11];
    const float* aW3 = (const float*)d_in[12]; const float* ab3 = (const float*)d_in[13];
    const float* sW1 = (const float*)d_in[14]; const float* sb1 = (const float*)d_in[15];
    const float* sW2 = (const float*)d_in[16]; const float* sb2 = (const float*)d_in[17];
    const float* sW3 = (const float*)d_in[18]; const float* sb3 = (const float*)d_in[19];
    const float* pW1 = (const float*)d_in[20]; const float* pb1 = (const float*)d_in[21];
    const float* pW2 = (const float*)d_in[22]; const float* pb2 = (const float*)d_in[23];
    const float* pW3 = (const float*)d_in[24]; const float* pb3 = (const float*)d_in[25];
    float* W = (float*)d_ws;
    float* out = (float*)d_out;
    ull* hqL2 = (ull*)(W + OFF_G);
    ull* hqL3 = hqL2 + (size_t)2 * TN * 256;
    int* ctrl = (int*)(hqL3 + (size_t)2 * TN * 256);
    unsigned short* pw1cb = (unsigned short*)(W + OFF_PW1CB);
    unsigned short* pw2b  = (unsigned short*)(W + OFF_PW2B);

    hipMemsetAsync(d_out, 0, (size_t)out_size * sizeof(float), stream);
    hipMemsetAsync(hqL2, 0, (size_t)4 * TN * 256 * sizeof(ull) + 1024, stream);

    k_pre0<<<TN + 2400, 256, 0, stream>>>(tokens, emb, W + OFF_X, Wih_f, Wih_b,
                                          W + OFF_WTF, W + OFF_WTB);
    k_pre1<<<58, 256, 0, stream>>>(aW1, aW2, sW1, sW2, pW1, pW2,
                                   W + OFF_AW1T, W + OFF_AW2T, W + OFF_SW1T, W + OFF_SW2T,
                                   W + OFF_PW1AT, W + OFF_PW1BT, pw1cb, pw2b);
    k_zx<<<dim3(96, 2), 256, 0, stream>>>(W + OFF_X, W + OFF_WTF, W + OFF_WTB, b_f, b_b,
                                          W + OFF_ZXF, W + OFF_ZXB);
    k_lstm_mb8<<<32, 256, 0, stream>>>(W + OFF_ZXF, W + OFF_ZXB, Whh_f, Whh_b, W + OFF_H,
                                       hqL2, hqL3, ctrl);
    k_attn<<<TN, 256, 0, stream>>>(W + OFF_H, W + OFF_AW1T, ab1, W + OFF_AW2T, ab2, aW3, ab3,
                                   W + OFF_ATTN);
    k_spans<<<NSPANS, 64, 0, stream>>>(W + OFF_ATTN, W + OFF_H, W + OFF_X, W + OFF_G,
                                       (int*)(W + OFF_I1), (int*)(W + OFF_I2));
    k_sm<<<(NSPANS + 31) / 32, 256, 0, stream>>>(W + OFF_G, W + OFF_SW1T, sb1, W + OFF_SW2T, sb2,
                                                 sW3, sb3, W + OFF_SM);
    k_sortsel<<<1, 1024, 0, stream>>>(W + OFF_SM, (int*)(W + OFF_I1), (int*)(W + OFF_I2),
                                      (int*)(W + OFF_SELK), (int*)(W + OFF_SELSPAN),
                                      W + OFF_SMF, out);
    k_AB<<<dim3(NSEL, 2), 256, 0, stream>>>(W + OFF_G, (int*)(W + OFF_SELSPAN), W + OFF_PW1AT,
                                            W + OFF_PW1BT, pb1, W + OFF_A, W + OFF_B);
    k_pairs_mfma<<<dim3(NSEL, 10), 256, 0, stream>>>(W + OFF_G, (int*)(W + OFF_SELSPAN),
                                                     W + OFF_SMF, W + OFF_A, W + OFF_B,
                                                     pw1cb, pw2b, pb2, pW3, pb3, out);
}

// Round 16
// 2191.177 us; speedup vs baseline: 1.3623x; 1.0100x over previous
//
#include <hip/hip_runtime.h>
#include <hip/hip_bf16.h>
#include <math.h>
#include <float.h>

#define TN      768
#define EMBD    300
#define XPAD    304
#define LSTMD   200
#define G4      800
#define STATE   400
#define HIDD    150
#define NPADC   160
#define SPAND   1101
#define KP      1120
#define NSPANS  7635
#define NSEL    307
#define SORTN   8192

typedef unsigned long long ull;
typedef __attribute__((ext_vector_type(8))) short bf16x8;
typedef __attribute__((ext_vector_type(4))) float mf32x4;

// ---- workspace offsets (in floats) ----
#define OFF_X       0u
#define OFF_ZXF     233472u
#define OFF_ZXB     847872u
#define OFF_H       1462272u
#define OFF_ATTN    1769472u
#define OFF_I1      1770496u
#define OFF_I2      1778176u
#define OFF_SM      1785856u
#define OFF_SELK    1793536u
#define OFF_SELSPAN 1794048u
#define OFF_SMF     1794560u
#define OFF_A       1795072u
#define OFF_B       1844224u
#define OFF_WTF     1893376u
#define OFF_WTB     2133376u
#define OFF_AW1T    2373376u
#define OFF_AW2T    2437376u
#define OFF_SW1T    2461376u
#define OFF_SW2T    2640576u
#define OFF_PW1AT   2664576u
#define OFF_PW1BT   2843776u
#define OFF_G       3226176u
#define OFF_PW1CB   11777376u   /* bf16 [160][1120] = 89600 floats */
#define OFF_PW2B    11866976u   /* bf16 [160][160]  = 12800 floats */
// hqL2 + hqL3 mailboxes + ctrl alias the head of the G region (k_spans
// overwrites g rows strictly after the LSTM in stream order).

#define REP50(M) M(0) M(1) M(2) M(3) M(4) M(5) M(6) M(7) M(8) M(9) \
 M(10) M(11) M(12) M(13) M(14) M(15) M(16) M(17) M(18) M(19) \
 M(20) M(21) M(22) M(23) M(24) M(25) M(26) M(27) M(28) M(29) \
 M(30) M(31) M(32) M(33) M(34) M(35) M(36) M(37) M(38) M(39) \
 M(40) M(41) M(42) M(43) M(44) M(45) M(46) M(47) M(48) M(49)

__device__ __forceinline__ float sigf(float x) { return 1.f / (1.f + __expf(-x)); }
__device__ __forceinline__ float tanhf_(float x) {
    x = fminf(15.f, fmaxf(-15.f, x));
    float e = __expf(2.f * x);
    return (e - 1.f) / (e + 1.f);
}
__device__ __forceinline__ unsigned short f2bf(float v) {
    __hip_bfloat16 h = __float2bfloat16(v);
    return *(unsigned short*)&h;
}
// LDS-only barrier: syncs waves + drains LDS ops, but lets global loads/stores
// stay in flight (no vmcnt(0) drain that __syncthreads would emit).
__device__ __forceinline__ void lds_barrier() {
    asm volatile("s_waitcnt lgkmcnt(0)" ::: "memory");
    __builtin_amdgcn_s_barrier();
    __builtin_amdgcn_sched_barrier(0);
}

// ---------------- fused gather + Wih transposes (sequential, pre-LSTM) -----
__global__ void k_pre0(const int* __restrict__ tokens, const float* __restrict__ emb,
                       float* __restrict__ x, const float* __restrict__ Wih_f,
                       const float* __restrict__ Wih_b, float* __restrict__ wtf,
                       float* __restrict__ wtb) {
    int b = blockIdx.x, tid = threadIdx.x;
    if (b < TN) {
        int tok = tokens[b];
        for (int d = tid; d < XPAD; d += 256)
            x[b * XPAD + d] = (d < EMBD) ? emb[(size_t)tok * EMBD + d] : 0.f;
    } else if (b < TN + 1200) {
        int bb = b - TN;
        int k = bb >> 2, n = ((bb & 3) << 8) + tid;
        if (n < G4) wtf[(size_t)k * G4 + n] = Wih_f[(size_t)n * EMBD + k];
    } else {
        int bb = b - TN - 1200;
        int k = bb >> 2, n = ((bb & 3) << 8) + tid;
        if (n < G4) wtb[(size_t)k * G4 + n] = Wih_b[(size_t)n * EMBD + k];
    }
}

// ---------------- fused small-weight prep (sequential, pre-LSTM) ----------
__device__ void prep_tr(const float* __restrict__ src, float* __restrict__ dst,
                        int N, int K, int stride, int off, int Npad, int totalK,
                        int part, int nparts, int tid) {
    int total = totalK * Npad;
    for (int idx = part * 256 + tid; idx < total; idx += nparts * 256) {
        int k = idx / Npad, n = idx - k * Npad;
        dst[idx] = (k < K && n < N) ? src[(size_t)n * stride + off + k] : 0.f;
    }
}
__device__ void prep_bf(const float* __restrict__ src, unsigned short* __restrict__ dst,
                        int R, int C, int stride, int off, int NR, int NC,
                        int part, int nparts, int tid) {
    int total = NR * NC;
    for (int idx = part * 256 + tid; idx < total; idx += nparts * 256) {
        int r = idx / NC, c = idx - r * NC;
        float v = (r < R && c < C) ? src[(size_t)r * stride + off + c] : 0.f;
        dst[idx] = f2bf(v);
    }
}
__global__ void k_pre1(const float* __restrict__ aW1, const float* __restrict__ aW2,
                       const float* __restrict__ sW1, const float* __restrict__ sW2,
                       const float* __restrict__ pW1, const float* __restrict__ pW2,
                       float* __restrict__ aW1T, float* __restrict__ aW2T,
                       float* __restrict__ sW1T, float* __restrict__ sW2T,
                       float* __restrict__ pW1AT, float* __restrict__ pW1BT,
                       unsigned short* __restrict__ pw1cb,
                       unsigned short* __restrict__ pw2b) {
    int p = blockIdx.x, tid = threadIdx.x;
    if (p < 4)       prep_tr(aW1, aW1T, 150, 400, 400, 0, 160, 400, p, 4, tid);
    else if (p < 6)  prep_tr(aW2, aW2T, 150, 150, 150, 0, 160, 150, p - 4, 2, tid);
    else if (p < 18) prep_tr(sW1, sW1T, 150, SPAND, SPAND, 0, 160, KP, p - 6, 12, tid);
    else if (p < 20) prep_tr(sW2, sW2T, 150, 150, 150, 0, 160, 150, p - 18, 2, tid);
    else if (p < 32) prep_tr(pW1, pW1AT, 150, SPAND, 3303, 0, 160, KP, p - 20, 12, tid);
    else if (p < 44) prep_tr(pW1, pW1BT, 150, SPAND, 3303, 1101, 160, KP, p - 32, 12, tid);
    else if (p < 56) prep_bf(pW1, pw1cb, 150, SPAND, 3303, 2202, 160, KP, p - 44, 12, tid);
    else             prep_bf(pW2, pw2b, 150, 150, 150, 0, 160, 160, p - 56, 2, tid);
}

// ---------------- input projections zx = x @ Wih^T + b ----------------
__global__ void k_zx(const float* __restrict__ x, const float* __restrict__ WTf,
                     const float* __restrict__ WTb, const float* __restrict__ bf,
                     const float* __restrict__ bb, float* __restrict__ zxf,
                     float* __restrict__ zxb) {
    __shared__ float xl[8 * XPAD];
    int tid = threadIdx.x;
    int bm = blockIdx.x, dir = blockIdx.y;
    for (int l = tid; l < 8 * XPAD; l += 256) xl[l] = x[(size_t)(bm * 8) * XPAD + l];
    __syncthreads();
    const float* WT = dir ? WTb : WTf;
    const float* bv = dir ? bb : bf;
    float* zx = dir ? zxb : zxf;
    for (int jj = 0; jj < 4; ++jj) {
        int n = tid + 256 * jj;
        if (n >= G4) break;
        float acc[8] = {0, 0, 0, 0, 0, 0, 0, 0};
        for (int k = 0; k < EMBD; ++k) {
            float wv = WT[(size_t)k * G4 + n];
#pragma unroll
            for (int r = 0; r < 8; ++r) acc[r] = fmaf(xl[r * XPAD + k], wv, acc[r]);
        }
        float bias = bv[n];
#pragma unroll
        for (int r = 0; r < 8; ++r) {
            int row = bm * 8 + r;
            int trow = dir ? (TN - 1 - row) : row;
            zx[(size_t)trow * G4 + n] = acc[r] + bias;
        }
    }
}

// ---------------- BiLSTM (R15-frozen: structural latency floor) ----------
__global__ __launch_bounds__(256, 1) void k_lstm_mb8(const float* __restrict__ zxf,
                                                     const float* __restrict__ zxb,
                                                     const float* __restrict__ Whh_f,
                                                     const float* __restrict__ Whh_b,
                                                     float* __restrict__ hcat,
                                                     ull* __restrict__ hqL2,
                                                     ull* __restrict__ hqL3,
                                                     int* __restrict__ ctrl) {
    int blk = blockIdx.x;
    int lane8 = blk & 7;
    if (lane8 >= 2) return;
    int dir = lane8, b = blk >> 3;
    int tid = threadIdx.x;
    __shared__ int s_mode;
    if (tid == 0) {
        unsigned xcc;
        asm volatile("s_getreg_b32 %0, hwreg(HW_REG_XCC_ID)" : "=s"(xcc));
        xcc &= 7u;
        __hip_atomic_store(&ctrl[dir * 4 + b], (int)(1u + xcc), __ATOMIC_RELAXED,
                           __HIP_MEMORY_SCOPE_AGENT);
        int v0, v1, v2, v3;
        do {
            v0 = __hip_atomic_load(&ctrl[dir * 4 + 0], __ATOMIC_RELAXED,
                                   __HIP_MEMORY_SCOPE_AGENT);
            v1 = __hip_atomic_load(&ctrl[dir * 4 + 1], __ATOMIC_RELAXED,
                                   __HIP_MEMORY_SCOPE_AGENT);
            v2 = __hip_atomic_load(&ctrl[dir * 4 + 2], __ATOMIC_RELAXED,
                                   __HIP_MEMORY_SCOPE_AGENT);
            v3 = __hip_atomic_load(&ctrl[dir * 4 + 3], __ATOMIC_RELAXED,
                                   __HIP_MEMORY_SCOPE_AGENT);
        } while (!v0 || !v1 || !v2 || !v3);
        s_mode = (v0 == v1 && v1 == v2 && v2 == v3) ? 1 : 0;
    }
    __syncthreads();
    int mode = s_mode;  // 1 = XCD-local L2 exchange; 0 = L3 (R4 path)

    const float* zx = dir ? zxb : zxf;
    const float* Whh = dir ? Whh_b : Whh_f;
    ull* hq2d = hqL2 + (size_t)dir * TN * 256;
    ull* hq3d = hqL3 + (size_t)dir * TN * 256;
    __shared__ __align__(16) float hprev[LSTMD];
    __shared__ float zl[200];
    bool active = tid < 200;
    int q = tid / 50, u = tid % 50;
    int gr_row = q * 200 + b * 50 + u;
    int grs = active ? gr_row : 0;
    const float4* wr = (const float4*)(Whh + (size_t)grs * LSTMD);
#define WDECL(i) float4 w##i = wr[i];
    REP50(WDECL)
#undef WDECL
    float c = 0.f;
    for (int l = tid; l < LSTMD; l += 256) hprev[l] = 0.f;
    int remote_idx = (tid < b * 50) ? tid : tid + 50;
    __syncthreads();
    float zpre = zx[grs];
    for (int t = 0; t < TN; ++t) {
        float acc = zpre;
        const float4* h4 = (const float4*)hprev;
#define WFMA(i) { float4 hv = h4[i]; \
        acc = fmaf(w##i.x, hv.x, acc); acc = fmaf(w##i.y, hv.y, acc); \
        acc = fmaf(w##i.z, hv.z, acc); acc = fmaf(w##i.w, hv.w, acc); }
        REP50(WFMA)
#undef WFMA
        if (active) zl[tid] = acc;
        lds_barrier();
        int trow = dir ? (TN - 1 - t) : t;
        if (tid < 50) {
            float zi = zl[tid], zf = zl[50 + tid], zg = zl[100 + tid], zo = zl[150 + tid];
            c = sigf(zf) * c + sigf(zi) * tanhf_(zg);
            float h = sigf(zo) * tanhf_(c);
            hcat[(size_t)trow * STATE + dir * LSTMD + b * 50 + tid] = h;
            hprev[b * 50 + tid] = h;
            if (t + 1 < TN) {
                ull pk = (ull)__float_as_uint(h) | ((ull)(unsigned)(t + 1) << 32);
                size_t slot = (size_t)t * 256 + b * 50 + tid;
                if (mode) {
                    (void)__hip_atomic_exchange(&hq2d[slot], pk, __ATOMIC_RELAXED,
                                                __HIP_MEMORY_SCOPE_WORKGROUP);
                } else {
                    __hip_atomic_store(&hq3d[slot], pk, __ATOMIC_RELAXED,
                                       __HIP_MEMORY_SCOPE_AGENT);
                }
            }
        }
        if (t + 1 < TN) {
            zpre = zx[(size_t)(t + 1) * G4 + grs];  // stays in flight across barrier
            if (tid < 150) {
                size_t slot = (size_t)t * 256 + remote_idx;
                ull v;
                if (mode) {
                    for (;;) {
                        ull probe = ~0ull;
                        __hip_atomic_compare_exchange_strong(
                            &hq2d[slot], &probe, ~0ull, __ATOMIC_RELAXED,
                            __ATOMIC_RELAXED, __HIP_MEMORY_SCOPE_WORKGROUP);
                        if ((unsigned)(probe >> 32) == (unsigned)(t + 1)) {
                            v = probe; break;
                        }
                    }
                } else {
                    do {
                        v = __hip_atomic_load(&hq3d[slot], __ATOMIC_RELAXED,
                                              __HIP_MEMORY_SCOPE_AGENT);
                    } while ((unsigned)(v >> 32) != (unsigned)(t + 1));
                }
                hprev[remote_idx] = __uint_as_float((unsigned)v);
            }
            lds_barrier();
        }
    }
}

// ---------------- attention FFNN: per-token scalar (float4 loads) ----------
__global__ void k_attn(const float* __restrict__ hcat, const float* __restrict__ aW1T,
                       const float* __restrict__ ab1, const float* __restrict__ aW2T,
                       const float* __restrict__ ab2, const float* __restrict__ aW3,
                       const float* __restrict__ ab3, float* __restrict__ attn) {
    __shared__ __align__(16) float hrow[STATE];
    __shared__ float l1[NPADC];
    __shared__ float l2[NPADC];
    __shared__ float red[256];
    int t = blockIdx.x, tid = threadIdx.x;
    if (tid < 100)
        ((float4*)hrow)[tid] = ((const float4*)(hcat + (size_t)t * STATE))[tid];
    __syncthreads();
    if (tid < HIDD) {
        float acc = ab1[tid];
        for (int k = 0; k < STATE; ++k) acc = fmaf(hrow[k], aW1T[(size_t)k * NPADC + tid], acc);
        l1[tid] = fmaxf(acc, 0.f);
    }
    __syncthreads();
    if (tid < HIDD) {
        float acc = ab2[tid];
        for (int k = 0; k < HIDD; ++k) acc = fmaf(l1[k], aW2T[(size_t)k * NPADC + tid], acc);
        l2[tid] = fmaxf(acc, 0.f);
    }
    __syncthreads();
    float partial = (tid < HIDD) ? l2[tid] * aW3[tid] : 0.f;
    red[tid] = partial;
    __syncthreads();
    for (int s = 128; s > 0; s >>= 1) {
        if (tid < s) red[tid] += red[tid + s];
        __syncthreads();
    }
    if (tid == 0) attn[t] = red[0] + ab3[0];
}

// ---------------- span construction: fully float4-vectorized ---------------
// Same math as before (softmax weights uniform per block; pooled = sum of
// w[k] * x-row float4s — per-component order identical to the scalar loop).
__global__ void k_spans(const float* __restrict__ attn, const float* __restrict__ hcat,
                        const float* __restrict__ x, float* __restrict__ g,
                        int* __restrict__ i1s, int* __restrict__ i2s) {
    int s = blockIdx.x;
    int n = 1, base = 0;
    while (s >= base + (TN - n + 1)) { base += TN - n + 1; n++; }
    int a = s - base, b = a + n - 1;
    int lane = threadIdx.x;  // 0..127
    float e[10];
    float mx = -FLT_MAX;
#pragma unroll
    for (int k = 0; k < 10; ++k)
        if (k < n) { e[k] = attn[a + k]; mx = fmaxf(mx, e[k]); }
    float ssum = 0.f;
#pragma unroll
    for (int k = 0; k < 10; ++k)
        if (k < n) { e[k] = __expf(e[k] - mx); ssum += e[k]; }
    float w[10];
#pragma unroll
    for (int k = 0; k < 10; ++k) w[k] = (k < n) ? e[k] / ssum : 0.f;

    float* grow = g + (size_t)s * KP;
    float4* grow4 = (float4*)grow;
    const float4* ha4 = (const float4*)(hcat + (size_t)a * STATE);
    const float4* hb4 = (const float4*)(hcat + (size_t)b * STATE);
    if (lane < 100) grow4[lane] = ha4[lane];                    // h[a]: 400f
    if (lane < 100) grow4[100 + lane] = hb4[lane];              // h[b]: 400f
    if (lane < 75) {                                            // pooled: 300f
        float4 p = {0.f, 0.f, 0.f, 0.f};
#pragma unroll
        for (int k = 0; k < 10; ++k)
            if (k < n) {
                float4 xv = ((const float4*)(x + (size_t)(a + k) * XPAD))[lane];
                p.x = fmaf(w[k], xv.x, p.x);
                p.y = fmaf(w[k], xv.y, p.y);
                p.z = fmaf(w[k], xv.z, p.z);
                p.w = fmaf(w[k], xv.w, p.w);
            }
        grow4[200 + lane] = p;
    }
    if (lane == 0) { grow[1100] = (float)n; i1s[s] = a; i2s[s] = b; }
    if (lane >= 101 && lane < 120) grow[1000 + lane] = 0.f;     // pad 1101..1119
}

// ---------------- span FFNN -> sm scores (float4 staging) ----------------
__global__ void k_sm(const float* __restrict__ g, const float* __restrict__ sW1T,
                     const float* __restrict__ sb1, const float* __restrict__ sW2T,
                     const float* __restrict__ sb2, const float* __restrict__ sW3,
                     const float* __restrict__ sb3, float* __restrict__ smo) {
    __shared__ float As[32 * 33];
    __shared__ __align__(16) float Bs[32 * NPADC];
    __shared__ float L1[32 * 161];
    int tid = threadIdx.x;
    int tx = tid & 31, ty = tid >> 5;
    int row0 = blockIdx.x * 32;
    float acc[4][5] = {};
    for (int kb = 0; kb < KP; kb += 32) {
        {   // A: 32 rows x 32 cols = 256 float4 loads (1/thread)
            int r = tid >> 3, c4 = (tid & 7) * 4;
            int gr = row0 + r;
            float4 v = {0.f, 0.f, 0.f, 0.f};
            if (gr < NSPANS) v = *(const float4*)&g[(size_t)gr * KP + kb + c4];
            As[r * 33 + c4 + 0] = v.x;
            As[r * 33 + c4 + 1] = v.y;
            As[r * 33 + c4 + 2] = v.z;
            As[r * 33 + c4 + 3] = v.w;
        }
        for (int l = tid; l < 32 * 40; l += 256) {  // B: 1280 float4 (5/thread)
            int r = l / 40, c4 = (l - r * 40) * 4;
            *(float4*)&Bs[r * NPADC + c4] =
                *(const float4*)&sW1T[(size_t)(kb + r) * NPADC + c4];
        }
        __syncthreads();
        for (int kk = 0; kk < 32; ++kk) {
            float bv[5];
#pragma unroll
            for (int jn = 0; jn < 5; ++jn) bv[jn] = Bs[kk * NPADC + tx + 32 * jn];
#pragma unroll
            for (int i4 = 0; i4 < 4; ++i4) {
                float av = As[(ty * 4 + i4) * 33 + kk];
#pragma unroll
                for (int jn = 0; jn < 5; ++jn) acc[i4][jn] = fmaf(av, bv[jn], acc[i4][jn]);
            }
        }
        __syncthreads();
    }
#pragma unroll
    for (int i4 = 0; i4 < 4; ++i4)
#pragma unroll
        for (int jn = 0; jn < 5; ++jn) {
            int nn = tx + 32 * jn;
            float v = acc[i4][jn] + (nn < HIDD ? sb1[nn] : 0.f);
            L1[(ty * 4 + i4) * 161 + nn] = fmaxf(v, 0.f);
        }
    __syncthreads();
    float acc2[4][5] = {};
    for (int kk = 0; kk < HIDD; ++kk) {
        float bv[5];
#pragma unroll
        for (int jn = 0; jn < 5; ++jn) bv[jn] = sW2T[(size_t)kk * NPADC + tx + 32 * jn];
#pragma unroll
        for (int i4 = 0; i4 < 4; ++i4) {
            float av = L1[(ty * 4 + i4) * 161 + kk];
#pragma unroll
            for (int jn = 0; jn < 5; ++jn) acc2[i4][jn] = fmaf(av, bv[jn], acc2[i4][jn]);
        }
    }
    float part[4];
#pragma unroll
    for (int i4 = 0; i4 < 4; ++i4) {
        float p = 0.f;
#pragma unroll
        for (int jn = 0; jn < 5; ++jn) {
            int nn = tx + 32 * jn;
            float v = acc2[i4][jn] + (nn < HIDD ? sb2[nn] : 0.f);
            v = fmaxf(v, 0.f);
            p = fmaf(v, (nn < HIDD ? sW3[nn] : 0.f), p);
        }
        part[i4] = p;
    }
    for (int s = 16; s > 0; s >>= 1)
#pragma unroll
        for (int i4 = 0; i4 < 4; ++i4) part[i4] += __shfl_xor(part[i4], s, 32);
    if (tx == 0)
#pragma unroll
        for (int i4 = 0; i4 < 4; ++i4) {
            int gr = row0 + ty * 4 + i4;
            if (gr < NSPANS) smo[gr] = part[i4] + sb3[0];
        }
}

// ---------------- sort + greedy filter + selection ----------------
__global__ __launch_bounds__(1024) void k_sortsel(const float* __restrict__ sm,
                                                  const int* __restrict__ i1s,
                                                  const int* __restrict__ i2s,
                                                  int* __restrict__ selk,
                                                  int* __restrict__ selspan,
                                                  float* __restrict__ smf,
                                                  float* __restrict__ out) {
    __shared__ float ks[SORTN];
    __shared__ unsigned short id16[SORTN];
    __shared__ int ka2[512];
    __shared__ int va2[512];
    int tid = threadIdx.x;
    for (int i = tid; i < SORTN; i += 1024) {
        ks[i] = (i < NSPANS) ? sm[i] : -FLT_MAX;
        id16[i] = (unsigned short)i;
    }
    __syncthreads();
    for (int size = 2; size <= SORTN; size <<= 1) {
        for (int stride = size >> 1; stride > 0; stride >>= 1) {
            for (int t = tid; t < SORTN / 2; t += 1024) {
                int i = ((t & ~(stride - 1)) << 1) | (t & (stride - 1));
                int j = i + stride;
                float ki = ks[i], kj = ks[j];
                unsigned short ai = id16[i], aj = id16[j];
                bool less_ji = (kj > ki) || (kj == ki && aj < ai);
                bool asc = ((i & size) == 0);
                if (less_ji == asc) {
                    ks[i] = kj; ks[j] = ki;
                    id16[i] = aj; id16[j] = ai;
                }
            }
            __syncthreads();
        }
    }
    unsigned* abu = reinterpret_cast<unsigned*>(ks);
    for (int k = tid; k < NSPANS; k += 1024) {
        int sid = id16[k];
        abu[k] = (unsigned)i1s[sid] | ((unsigned)i2s[sid] << 16);
    }
    __syncthreads();
    if (tid < 64) {
        int l = tid;
        unsigned tk = 0;
        int cnt = 0;
        for (int k = 0; k < NSPANS && cnt < NSEL; ++k) {
            unsigned ab = abu[k];
            int a = (int)(ab & 0xFFFFu), b = (int)(ab >> 16);
            int lo = a - (l << 5), hi = b - (l << 5);
            lo = lo < 0 ? 0 : lo;
            hi = hi > 31 ? 31 : hi;
            unsigned m = 0;
            if (hi >= lo) {
                unsigned upper = (hi == 31) ? 0xFFFFFFFFu : ((1u << (hi + 1)) - 1u);
                m = upper & ~((1u << lo) - 1u);
            }
            bool cov = ((tk & m) == m);
            bool all_taken = __all((int)cov);
            int la = a >> 5, lb = b >> 5;
            unsigned long long bal_a = __ballot((int)((l == la) && ((tk >> (a & 31)) & 1u)));
            unsigned long long bal_b = __ballot((int)((l == lb) && ((tk >> (b & 31)) & 1u)));
            bool ok = all_taken || (bal_a == 0ull && bal_b == 0ull);
            if (ok) {
                tk |= m;
                if (l == 0) selk[cnt] = k;
                cnt++;
            }
        }
    }
    __syncthreads();
    if (tid < 512) {
        int r = tid;
        int key = 0x7FFFFFFF;
        if (r < NSEL) {
            int k = selk[r];
            int a = (int)(abu[k] & 0xFFFFu);
            key = (a << 9) | r;
        }
        ka2[r] = key;
        va2[r] = r;
    }
    __syncthreads();
    for (int size = 2; size <= 512; size <<= 1) {
        for (int stride = size >> 1; stride > 0; stride >>= 1) {
            if (tid < 256) {
                int t = tid;
                int i = ((t & ~(stride - 1)) << 1) | (t & (stride - 1));
                int j = i + stride;
                int ki = ka2[i], kj = ka2[j];
                bool asc = ((i & size) == 0);
                if ((kj < ki) == asc) {
                    ka2[i] = kj; ka2[j] = ki;
                    int vi = va2[i]; va2[i] = va2[j]; va2[j] = vi;
                }
            }
            __syncthreads();
        }
    }
    if (tid < NSEL) {
        int r = va2[tid];
        int k = selk[r];
        int sid = id16[k];
        unsigned ab = abu[k];
        selspan[tid] = sid;
        smf[tid] = sm[sid];
        out[NSEL * NSEL + tid] = (float)(ab & 0xFFFFu);
        out[NSEL * NSEL + NSEL + tid] = (float)(ab >> 16);
    }
}

// ---------------- A_i = g_i @ pW1a^T + pb1 ; B_j = g_j @ pW1b^T ----------------
__global__ void k_AB(const float* __restrict__ g, const int* __restrict__ selspan,
                     const float* __restrict__ pW1aT, const float* __restrict__ pW1bT,
                     const float* __restrict__ pb1, float* __restrict__ Aw,
                     float* __restrict__ Bw) {
    __shared__ __align__(16) float grow[KP];
    int r = blockIdx.x, which = blockIdx.y;
    int sid = selspan[r];
    int tid = threadIdx.x;
    for (int d = tid; d < 280; d += 256)
        ((float4*)grow)[d] = ((const float4*)(g + (size_t)sid * KP))[d];
    __syncthreads();
    if (tid < NPADC) {
        const float* WT = which ? pW1bT : pW1aT;
        float acc = 0.f;
        for (int k = 0; k < KP; ++k) acc = fmaf(grow[k], WT[(size_t)k * NPADC + tid], acc);
        if (which == 0) acc += (tid < HIDD ? pb1[tid] : 0.f);
        (which ? Bw : Aw)[(size_t)r * NPADC + tid] = acc;
    }
}

// ---------------- pair FFNN via bf16 MFMA + sij scatter ----------------
__global__ __launch_bounds__(256, 1) void k_pairs_mfma(
    const float* __restrict__ g, const int* __restrict__ selspan,
    const float* __restrict__ smf, const float* __restrict__ Aw,
    const float* __restrict__ Bw, const unsigned short* __restrict__ pw1cb,
    const unsigned short* __restrict__ pw2b, const float* __restrict__ pb2,
    const float* __restrict__ pW3, const float* __restrict__ pb3,
    float* __restrict__ out) {
    int i = blockIdx.x;
    int j0 = blockIdx.y * 32;
    if (j0 >= i) return;
    __shared__ __align__(16) unsigned short Abuf[32][232];
    __shared__ __align__(16) unsigned short Btb[160][232];
    __shared__ __align__(16) unsigned short L1b[32][168];
    __shared__ float BwS[32][160];
    __shared__ float AwS[160];
    __shared__ float GiS[224];
    __shared__ float pb2S[160], pw3S[160];
    __shared__ float parts[4][32];
    int tid = threadIdx.x;
    int lane = tid & 63, wv = tid >> 6;
    int l15 = lane & 15, lg = lane >> 4;
    int sidi = selspan[i];

    if (tid < 160) {
        AwS[tid] = Aw[(size_t)i * NPADC + tid];
        pb2S[tid] = (tid < HIDD) ? pb2[tid] : 0.f;
        pw3S[tid] = (tid < HIDD) ? pW3[tid] : 0.f;
    }
    for (int idx = tid; idx < 32 * 160; idx += 256) {
        int r = idx / 160; int c = idx - r * 160;
        int j = j0 + r;
        BwS[r][c] = Bw[(size_t)(j < i ? j : 0) * NPADC + c];
    }
    mf32x4 acc[2][3];
#pragma unroll
    for (int m = 0; m < 2; ++m)
#pragma unroll
        for (int t = 0; t < 3; ++t) acc[m][t] = (mf32x4){0.f, 0.f, 0.f, 0.f};

    for (int kc = 0; kc < KP; kc += 224) {
        if (tid < 56)
            *(float4*)&GiS[tid * 4] = *(const float4*)&g[(size_t)sidi * KP + kc + tid * 4];
        for (int idx = tid; idx < 160 * 28; idx += 256) {
            int r = idx / 28, s = idx - r * 28;
            uint4 v = *(const uint4*)(pw1cb + (size_t)r * 1120 + kc + s * 8);
            *(uint4*)&Btb[r][s * 8] = v;
        }
        __syncthreads();
        for (int idx = tid; idx < 32 * 56; idx += 256) {
            int r = idx / 56, s = idx - r * 56;
            int j = j0 + r;
            float4 gj = {0.f, 0.f, 0.f, 0.f};
            if (j < i) gj = *(const float4*)&g[(size_t)selspan[j] * KP + kc + s * 4];
            float4 gi = *(const float4*)&GiS[s * 4];
            ushort4 u;
            u.x = f2bf(gj.x * gi.x); u.y = f2bf(gj.y * gi.y);
            u.z = f2bf(gj.z * gi.z); u.w = f2bf(gj.w * gi.w);
            *(ushort4*)&Abuf[r][s * 4] = u;
        }
        __syncthreads();
#pragma unroll
        for (int kk = 0; kk < 7; ++kk) {
            int ko = kk * 32 + lg * 8;
            bf16x8 a0 = *(const bf16x8*)&Abuf[l15][ko];
            bf16x8 a1 = *(const bf16x8*)&Abuf[16 + l15][ko];
#pragma unroll
            for (int t = 0; t < 3; ++t) {
                int n = wv + 4 * t;
                if (n < 10) {
                    bf16x8 bb = *(const bf16x8*)&Btb[n * 16 + l15][ko];
                    acc[0][t] = __builtin_amdgcn_mfma_f32_16x16x32_bf16(a0, bb, acc[0][t], 0, 0, 0);
                    acc[1][t] = __builtin_amdgcn_mfma_f32_16x16x32_bf16(a1, bb, acc[1][t], 0, 0, 0);
                }
            }
        }
        __syncthreads();
    }
#pragma unroll
    for (int m = 0; m < 2; ++m)
#pragma unroll
        for (int t = 0; t < 3; ++t) {
            int n = wv + 4 * t;
            if (n < 10) {
#pragma unroll
                for (int q = 0; q < 4; ++q) {
                    int row = m * 16 + lg * 4 + q;
                    int col = n * 16 + l15;
                    float v = acc[m][t][q] + AwS[col] + BwS[row][col];
                    L1b[row][col] = f2bf(fmaxf(v, 0.f));
                }
            }
        }
    for (int idx = tid; idx < 160 * 20; idx += 256) {
        int r = idx / 20, s = idx - r * 20;
        *(uint4*)&Btb[r][s * 8] = *(const uint4*)(pw2b + (size_t)r * 160 + s * 8);
    }
    __syncthreads();
    mf32x4 acc2[2][3];
#pragma unroll
    for (int m = 0; m < 2; ++m)
#pragma unroll
        for (int t = 0; t < 3; ++t) acc2[m][t] = (mf32x4){0.f, 0.f, 0.f, 0.f};
#pragma unroll
    for (int kk = 0; kk < 5; ++kk) {
        int ko = kk * 32 + lg * 8;
        bf16x8 a0 = *(const bf16x8*)&L1b[l15][ko];
        bf16x8 a1 = *(const bf16x8*)&L1b[16 + l15][ko];
#pragma unroll
        for (int t = 0; t < 3; ++t) {
            int n = wv + 4 * t;
            if (n < 10) {
                bf16x8 bb = *(const bf16x8*)&Btb[n * 16 + l15][ko];
                acc2[0][t] = __builtin_amdgcn_mfma_f32_16x16x32_bf16(a0, bb, acc2[0][t], 0, 0, 0);
                acc2[1][t] = __builtin_amdgcn_mfma_f32_16x16x32_bf16(a1, bb, acc2[1][t], 0, 0, 0);
            }
        }
    }
    float s[2][4] = {};
#pragma unroll
    for (int m = 0; m < 2; ++m)
#pragma unroll
        for (int t = 0; t < 3; ++t) {
            int n = wv + 4 * t;
            if (n < 10) {
#pragma unroll
                for (int q = 0; q < 4; ++q) {
                    int col = n * 16 + l15;
                    float v = fmaxf(acc2[m][t][q] + pb2S[col], 0.f);
                    s[m][q] = fmaf(v, pw3S[col], s[m][q]);
                }
            }
        }
#pragma unroll
    for (int off = 1; off < 16; off <<= 1)
#pragma unroll
        for (int m = 0; m < 2; ++m)
#pragma unroll
            for (int q = 0; q < 4; ++q) s[m][q] += __shfl_xor(s[m][q], off);
    if (l15 == 0) {
#pragma unroll
        for (int m = 0; m < 2; ++m)
#pragma unroll
            for (int q = 0; q < 4; ++q) parts[wv][m * 16 + lg * 4 + q] = s[m][q];
    }
    __syncthreads();
    if (tid < 32) {
        float sa = parts[0][tid] + parts[1][tid] + parts[2][tid] + parts[3][tid];
        int j = j0 + tid;
        if (j < i) out[(size_t)i * NSEL + j] = smf[i] + smf[j] + sa + pb3[0];
    }
}

extern "C" void kernel_launch(void* const* d_in, const int* in_sizes, int n_in,
                              void* d_out, int out_size, void* d_ws, size_t ws_size,
                              hipStream_t stream) {
    (void)in_sizes; (void)n_in; (void)ws_size;
    const int* tokens  = (const int*)d_in[0];
    const float* emb   = (const float*)d_in[1];
    const float* Wih_f = (const float*)d_in[2];
    const float* Whh_f = (const float*)d_in[3];
    const float* b_f   = (const float*)d_in[4];
    const float* Wih_b = (const float*)d_in[5];
    const float* Whh_b = (const float*)d_in[6];
    const float* b_b   = (const float*)d_in[7];
    const float* aW1 = (const float*)d_in[8];  const float* ab1 = (const float*)d_in[9];
    const float* aW2 = (const float*)d_in[10]; const float* ab2 = (const float*)d_in[11];
    const float* aW3 = (const float*)d_in[12]; const float* ab3 = (const float*)d_in[13];
    const float* sW1 = (const float*)d_in[14]; const float* sb1 = (const float*)d_in[15];
    const float* sW2 = (const float*)d_in[16]; const float* sb2 = (const float*)d_in[17];
    const float* sW3 = (const float*)d_in[18]; const float* sb3 = (const float*)d_in[19];
    const float* pW1 = (const float*)d_in[20]; const float* pb1 = (const float*)d_in[21];
    const float* pW2 = (const float*)d_in[22]; const float* pb2 = (const float*)d_in[23];
    const float* pW3 = (const float*)d_in[24]; const float* pb3 = (const float*)d_in[25];
    float* W = (float*)d_ws;
    float* out = (float*)d_out;
    ull* hqL2 = (ull*)(W + OFF_G);
    ull* hqL3 = hqL2 + (size_t)2 * TN * 256;
    int* ctrl = (int*)(hqL3 + (size_t)2 * TN * 256);
    unsigned short* pw1cb = (unsigned short*)(W + OFF_PW1CB);
    unsigned short* pw2b  = (unsigned short*)(W + OFF_PW2B);

    hipMemsetAsync(d_out, 0, (size_t)out_size * sizeof(float), stream);
    hipMemsetAsync(hqL2, 0, (size_t)4 * TN * 256 * sizeof(ull) + 1024, stream);

    k_pre0<<<TN + 2400, 256, 0, stream>>>(tokens, emb, W + OFF_X, Wih_f, Wih_b,
                                          W + OFF_WTF, W + OFF_WTB);
    k_pre1<<<58, 256, 0, stream>>>(aW1, aW2, sW1, sW2, pW1, pW2,
                                   W + OFF_AW1T, W + OFF_AW2T, W + OFF_SW1T, W + OFF_SW2T,
                                   W + OFF_PW1AT, W + OFF_PW1BT, pw1cb, pw2b);
    k_zx<<<dim3(96, 2), 256, 0, stream>>>(W + OFF_X, W + OFF_WTF, W + OFF_WTB, b_f, b_b,
                                          W + OFF_ZXF, W + OFF_ZXB);
    k_lstm_mb8<<<32, 256, 0, stream>>>(W + OFF_ZXF, W + OFF_ZXB, Whh_f, Whh_b, W + OFF_H,
                                       hqL2, hqL3, ctrl);
    k_attn<<<TN, 256, 0, stream>>>(W + OFF_H, W + OFF_AW1T, ab1, W + OFF_AW2T, ab2, aW3, ab3,
                                   W + OFF_ATTN);
    k_spans<<<NSPANS, 128, 0, stream>>>(W + OFF_ATTN, W + OFF_H, W + OFF_X, W + OFF_G,
                                        (int*)(W + OFF_I1), (int*)(W + OFF_I2));
    k_sm<<<(NSPANS + 31) / 32, 256, 0, stream>>>(W + OFF_G, W + OFF_SW1T, sb1, W + OFF_SW2T, sb2,
                                                 sW3, sb3, W + OFF_SM);
    k_sortsel<<<1, 1024, 0, stream>>>(W + OFF_SM, (int*)(W + OFF_I1), (int*)(W + OFF_I2),
                                      (int*)(W + OFF_SELK), (int*)(W + OFF_SELSPAN),
                                      W + OFF_SMF, out);
    k_AB<<<dim3(NSEL, 2), 256, 0, stream>>>(W + OFF_G, (int*)(W + OFF_SELSPAN), W + OFF_PW1AT,
                                            W + OFF_PW1BT, pb1, W + OFF_A, W + OFF_B);
    k_pairs_mfma<<<dim3(NSEL, 10), 256, 0, stream>>>(W + OFF_G, (int*)(W + OFF_SELSPAN),
                                                     W + OFF_SMF, W + OFF_A, W + OFF_B,
                                                     pw1cb, pw2b, pb2, pW3, pb3, out);
}